// Round 1
// baseline (4248.301 us; speedup 1.0000x reference)
//
#include <hip/hip_runtime.h>
#include <math.h>

#define LEAKY(v) ((v) > 0.0f ? (v) : 0.01f * (v))

// ---------------- degree / norm ----------------
__global__ void k_init_deg(float* __restrict__ deg, int n) {
    int i = blockIdx.x * blockDim.x + threadIdx.x;
    if (i < n) deg[i] = 1.0f;  // self-loop
}

__global__ void k_scatter_deg(const int* __restrict__ ei, float* __restrict__ deg, int E) {
    int e = blockIdx.x * blockDim.x + threadIdx.x;
    if (e < E) atomicAdd(&deg[ei[E + e]], 1.0f);
}

__global__ void k_finish_dinv(float* __restrict__ d, int n) {
    int i = blockIdx.x * blockDim.x + threadIdx.x;
    if (i < n) d[i] = 1.0f / sqrtf(d[i]);
}

// ---------------- layer-0: propagate x (4-wide), then 4->200 GEMM ----------------
__global__ void k_prop_init4(const float* __restrict__ x, const float* __restrict__ dinv,
                             float* __restrict__ px, int n) {
    int v = blockIdx.x * blockDim.x + threadIdx.x;
    if (v < n) {
        float w = dinv[v]; w *= w;  // self-loop norm
        float4 xv = ((const float4*)x)[v];
        xv.x *= w; xv.y *= w; xv.z *= w; xv.w *= w;
        ((float4*)px)[v] = xv;
    }
}

__global__ void k_scatter4(const int* __restrict__ ei, const float* __restrict__ x,
                           const float* __restrict__ dinv, float* __restrict__ px, int E) {
    int e = blockIdx.x * blockDim.x + threadIdx.x;
    if (e < E) {
        int s = ei[e], d = ei[E + e];
        float w = dinv[s] * dinv[d];
        float4 xv = ((const float4*)x)[s];
        atomicAdd(&px[d * 4 + 0], xv.x * w);
        atomicAdd(&px[d * 4 + 1], xv.y * w);
        atomicAdd(&px[d * 4 + 2], xv.z * w);
        atomicAdd(&px[d * 4 + 3], xv.w * w);
    }
}

// p0 = px @ W0   (n x 4) @ (4 x 200), no bias/act (deferred into next consumer)
__global__ __launch_bounds__(256) void k_gemm_l0(const float* __restrict__ px,
                                                 const float* __restrict__ W0,
                                                 float* __restrict__ p0, int n) {
    __shared__ float Ws[800];
    for (int idx = threadIdx.x; idx < 800; idx += 256) Ws[idx] = W0[idx];
    __syncthreads();
    int gid = blockIdx.x * blockDim.x + threadIdx.x;
    if (gid < n * 200) {
        int v = gid / 200, c = gid - v * 200;
        float4 xv = ((const float4*)px)[v];
        p0[gid] = xv.x * Ws[c] + xv.y * Ws[200 + c] + xv.z * Ws[400 + c] + xv.w * Ws[600 + c];
    }
}

// ---------------- main GEMM: T = leaky(P + bprev) @ W   (M x 200)@(200 x 200) ----------------
// 80-row x 200-col tile per block, 8x8 register blocking, 250/256 active threads.
__global__ __launch_bounds__(256) void k_gemm200(const float* __restrict__ P,
                                                 const float* __restrict__ bprev,
                                                 const float* __restrict__ W,
                                                 float* __restrict__ T, int n) {
    __shared__ float As[8][80];
    __shared__ float Ws[8][200];
    const int tid = threadIdx.x;
    const int row0 = blockIdx.x * 80;
    const int rg = tid / 25;   // 0..9 for active threads
    const int cg = tid % 25;   // 0..24
    const bool active = tid < 250;
    float acc[8][8];
#pragma unroll
    for (int i = 0; i < 8; ++i)
#pragma unroll
        for (int j = 0; j < 8; ++j) acc[i][j] = 0.0f;

    for (int k0 = 0; k0 < 200; k0 += 8) {
        // stage A tile (80 rows x 8 k), fused bias + leaky-relu, transposed -> As[kk][row]
        for (int idx = tid; idx < 640; idx += 256) {
            int r = idx >> 3, kk = idx & 7;
            int row = row0 + r;
            float v = 0.0f;
            if (row < n) {
                v = P[row * 200 + k0 + kk] + bprev[k0 + kk];
                v = LEAKY(v);
            }
            As[kk][r] = v;
        }
        // stage W tile (8 k x 200 cols)
        for (int idx = tid; idx < 1600; idx += 256) {
            int kk = idx / 200, c = idx - kk * 200;
            Ws[kk][c] = W[(k0 + kk) * 200 + c];
        }
        __syncthreads();
        if (active) {
#pragma unroll
            for (int kk = 0; kk < 8; ++kk) {
                float a[8], w[8];
                *(float4*)&a[0] = *(const float4*)&As[kk][rg * 8];
                *(float4*)&a[4] = *(const float4*)&As[kk][rg * 8 + 4];
                *(float4*)&w[0] = *(const float4*)&Ws[kk][cg * 8];
                *(float4*)&w[4] = *(const float4*)&Ws[kk][cg * 8 + 4];
#pragma unroll
                for (int i = 0; i < 8; ++i)
#pragma unroll
                    for (int j = 0; j < 8; ++j) acc[i][j] += a[i] * w[j];
            }
        }
        __syncthreads();
    }
    if (active) {
#pragma unroll
        for (int i = 0; i < 8; ++i) {
            int r = row0 + rg * 8 + i;
            if (r < n) {
                float4 o0 = make_float4(acc[i][0], acc[i][1], acc[i][2], acc[i][3]);
                float4 o1 = make_float4(acc[i][4], acc[i][5], acc[i][6], acc[i][7]);
                *(float4*)&T[r * 200 + cg * 8] = o0;
                *(float4*)&T[r * 200 + cg * 8 + 4] = o1;
            }
        }
    }
}

// ---------------- propagation (200-wide) ----------------
// p[v] = dinv[v]^2 * t[v]  (self-loop term + zero-init in one pass)
__global__ void k_prop_init200(const float* __restrict__ t, const float* __restrict__ dinv,
                               float* __restrict__ p, int n) {
    int gid = blockIdx.x * blockDim.x + threadIdx.x;  // over n*50 float4s
    if (gid < n * 50) {
        int v = gid / 50;
        float w = dinv[v]; w *= w;
        float4 tv = ((const float4*)t)[gid];
        tv.x *= w; tv.y *= w; tv.z *= w; tv.w *= w;
        ((float4*)p)[gid] = tv;
    }
}

// p[dst] += t[src] * dinv[src]*dinv[dst]  (atomic scatter, 50 float4s per edge)
__global__ void k_scatter200(const int* __restrict__ ei, const float* __restrict__ t,
                             const float* __restrict__ dinv, float* __restrict__ p, int E) {
    int gid = blockIdx.x * blockDim.x + threadIdx.x;  // over E*50
    if (gid < E * 50) {
        int e = gid / 50, c4 = gid - e * 50;
        int s = ei[e], d = ei[E + e];
        float w = dinv[s] * dinv[d];
        float4 tv = ((const float4*)t)[s * 50 + c4];
        float* pd = &p[d * 200 + c4 * 4];
        atomicAdd(pd + 0, tv.x * w);
        atomicAdd(pd + 1, tv.y * w);
        atomicAdd(pd + 2, tv.z * w);
        atomicAdd(pd + 3, tv.w * w);
    }
}

// ---------------- pooling: per-graph mean of leaky(p3 + b3) ----------------
__global__ __launch_bounds__(256) void k_pool(const float* __restrict__ p3,
                                              const float* __restrict__ b3,
                                              const int* __restrict__ batch, int n_nodes,
                                              float* __restrict__ pooled) {
    __shared__ int sb[2];
    int g = blockIdx.x;
    if (threadIdx.x == 0) {
        int lo = 0, hi = n_nodes;
        while (lo < hi) { int m = (lo + hi) >> 1; if (batch[m] < g) lo = m + 1; else hi = m; }
        sb[0] = lo;
        int lo2 = lo, hi2 = n_nodes;
        while (lo2 < hi2) { int m = (lo2 + hi2) >> 1; if (batch[m] < g + 1) lo2 = m + 1; else hi2 = m; }
        sb[1] = lo2;
    }
    __syncthreads();
    int lo = sb[0], hi = sb[1];
    int c = threadIdx.x;
    if (c < 200) {
        float bc = b3[c];
        float s = 0.0f;
        for (int nidx = lo; nidx < hi; ++nidx) {
            float v = p3[nidx * 200 + c] + bc;
            s += LEAKY(v);
        }
        float cnt = (float)(hi - lo);
        pooled[g * 200 + c] = s / fmaxf(cnt, 1.0f);
    }
}

// ---------------- head MLP: [pooled | x_scalar] @ Wl1 + bl1 -> leaky -> @ Wl2 + bl2 ----------------
__global__ __launch_bounds__(128) void k_mlp(const float* __restrict__ pooled,
                                             const float* __restrict__ xs,
                                             const float* __restrict__ Wl1,
                                             const float* __restrict__ bl1,
                                             const float* __restrict__ Wl2,
                                             const float* __restrict__ bl2,
                                             float* __restrict__ out) {
    __shared__ float grow[204];
    __shared__ float partial[2];
    int g = blockIdx.x;
    int t = threadIdx.x;
    for (int idx = t; idx < 200; idx += 128) grow[idx] = pooled[g * 200 + idx];
    if (t < 4) grow[200 + t] = xs[g * 4 + t];
    __syncthreads();
    float s = bl1[t];
    for (int k = 0; k < 204; ++k) s += grow[k] * Wl1[k * 128 + t];
    s = LEAKY(s);
    float v = s * Wl2[t];
    for (int off = 32; off > 0; off >>= 1) v += __shfl_down(v, off, 64);
    if ((t & 63) == 0) partial[t >> 6] = v;
    __syncthreads();
    if (t == 0) out[g] = partial[0] + partial[1] + bl2[0];
}

extern "C" void kernel_launch(void* const* d_in, const int* in_sizes, int n_in,
                              void* d_out, int out_size, void* d_ws, size_t ws_size,
                              hipStream_t stream) {
    const float* x    = (const float*)d_in[0];
    const int*   ei   = (const int*)d_in[1];
    const float* xs   = (const float*)d_in[2];
    const int*   batch= (const int*)d_in[3];
    const float* W0   = (const float*)d_in[4];
    const float* b0   = (const float*)d_in[5];
    const float* W1   = (const float*)d_in[6];
    const float* b1   = (const float*)d_in[7];
    const float* W2   = (const float*)d_in[8];
    const float* b2   = (const float*)d_in[9];
    const float* W3   = (const float*)d_in[10];
    const float* b3   = (const float*)d_in[11];
    const float* Wl1  = (const float*)d_in[12];
    const float* bl1  = (const float*)d_in[13];
    const float* Wl2  = (const float*)d_in[14];
    const float* bl2  = (const float*)d_in[15];
    float* out = (float*)d_out;

    const int N = in_sizes[0] / 4;   // 50000 nodes
    const int E = in_sizes[1] / 2;   // 400000 edges
    const int G = in_sizes[2] / 4;   // 500 graphs

    char* ws = (char*)d_ws;
    size_t hbytes = (size_t)N * 200 * sizeof(float);      // 40 MB
    float* buf0   = (float*)ws;
    float* buf1   = (float*)(ws + hbytes);
    float* dinv   = (float*)(ws + 2 * hbytes);
    float* px     = (float*)(ws + 2 * hbytes + (size_t)N * sizeof(float));
    float* pooled = (float*)(ws + 2 * hbytes + (size_t)N * 5 * sizeof(float));

    const int B = 256;
    // degree / norm
    k_init_deg<<<(N + B - 1) / B, B, 0, stream>>>(dinv, N);
    k_scatter_deg<<<(E + B - 1) / B, B, 0, stream>>>(ei, dinv, E);
    k_finish_dinv<<<(N + B - 1) / B, B, 0, stream>>>(dinv, N);

    // layer 0: propagate x (4-wide) then 4->200 GEMM
    k_prop_init4<<<(N + B - 1) / B, B, 0, stream>>>(x, dinv, px, N);
    k_scatter4<<<(E + B - 1) / B, B, 0, stream>>>(ei, x, dinv, px, E);
    k_gemm_l0<<<(N * 200 + B - 1) / B, B, 0, stream>>>(px, W0, buf0, N);

    // layers 1..3: GEMM (bias+leaky of prev layer fused into A load) then propagate
    const float* Wcur[3]  = {W1, W2, W3};
    const float* bprev[3] = {b0, b1, b2};
    for (int L = 0; L < 3; ++L) {
        k_gemm200<<<(N + 79) / 80, 256, 0, stream>>>(buf0, bprev[L], Wcur[L], buf1, N);
        k_prop_init200<<<(N * 50 + B - 1) / B, B, 0, stream>>>(buf1, dinv, buf0, N);
        k_scatter200<<<(E * 50 + B - 1) / B, B, 0, stream>>>(ei, buf1, dinv, buf0, E);
    }

    // pool (applies leaky(p3 + b3)) + head MLP
    k_pool<<<G, 256, 0, stream>>>(buf0, b3, batch, N, pooled);
    k_mlp<<<G, 128, 0, stream>>>(pooled, xs, Wl1, bl1, Wl2, bl2, out);
}

// Round 2
// 1049.728 us; speedup vs baseline: 4.0470x; 4.0470x over previous
//
#include <hip/hip_runtime.h>
#include <math.h>

#define LEAKY(v) ((v) > 0.0f ? (v) : 0.01f * (v))

// ================= CSR build =================
__global__ void k_zero2(int* __restrict__ cnt, int* __restrict__ fill, int n) {
    int i = blockIdx.x * blockDim.x + threadIdx.x;
    if (i < n) { cnt[i] = 0; fill[i] = 0; }
}

__global__ void k_count(const int* __restrict__ ei, int* __restrict__ cnt, int E) {
    int e = blockIdx.x * blockDim.x + threadIdx.x;
    if (e < E) atomicAdd(&cnt[ei[E + e]], 1);
}

// exclusive scan of cnt[0..n-1] -> rowptr[0..n] (single 1024-thread block)
__global__ __launch_bounds__(1024) void k_scan(const int* __restrict__ cnt,
                                               int* __restrict__ rowptr, int n) {
    __shared__ int ssum[1024];
    const int t = threadIdx.x;
    const int chunk = (n + 1023) / 1024;
    const int lo = t * chunk;
    const int hi = min(lo + chunk, n);
    int s = 0;
    for (int i = lo; i < hi; ++i) s += cnt[i];
    ssum[t] = s;
    __syncthreads();
    for (int off = 1; off < 1024; off <<= 1) {
        int v = (t >= off) ? ssum[t - off] : 0;
        __syncthreads();
        ssum[t] += v;
        __syncthreads();
    }
    int base = (t == 0) ? 0 : ssum[t - 1];
    for (int i = lo; i < hi; ++i) { rowptr[i] = base; base += cnt[i]; }
    if (hi == n) rowptr[n] = base;  // benign multi-writer of the same total
}

__global__ void k_dinv(const int* __restrict__ cnt, float* __restrict__ dinv, int n) {
    int i = blockIdx.x * blockDim.x + threadIdx.x;
    if (i < n) dinv[i] = rsqrtf(1.0f + (float)cnt[i]);  // +1 self-loop
}

__global__ void k_fill(const int* __restrict__ ei, const float* __restrict__ dinv,
                       const int* __restrict__ rowptr, int* __restrict__ fill,
                       int* __restrict__ col, float* __restrict__ wgt, int E) {
    int e = blockIdx.x * blockDim.x + threadIdx.x;
    if (e < E) {
        int s = ei[e], d = ei[E + e];
        int pos = rowptr[d] + atomicAdd(&fill[d], 1);
        col[pos] = s;
        wgt[pos] = dinv[s] * dinv[d];
    }
}

// ================= layer-0: gather x (4-wide), then 4->200 GEMM =================
__global__ void k_gather4(const float* __restrict__ x, const float* __restrict__ dinv,
                          const int* __restrict__ rowptr, const int* __restrict__ col,
                          const float* __restrict__ wgt, float* __restrict__ px, int n) {
    int v = blockIdx.x * blockDim.x + threadIdx.x;
    if (v >= n) return;
    float w0 = dinv[v]; w0 *= w0;
    float4 xv = ((const float4*)x)[v];
    float4 acc = make_float4(xv.x * w0, xv.y * w0, xv.z * w0, xv.w * w0);
    int lo = rowptr[v], hi = rowptr[v + 1];
    for (int j = lo; j < hi; ++j) {
        int s = col[j]; float w = wgt[j];
        float4 sv = ((const float4*)x)[s];
        acc.x += sv.x * w; acc.y += sv.y * w; acc.z += sv.z * w; acc.w += sv.w * w;
    }
    ((float4*)px)[v] = acc;
}

// p0 = px @ W0   (n x 4) @ (4 x 200), no bias/act (deferred into next consumer)
__global__ __launch_bounds__(256) void k_gemm_l0(const float* __restrict__ px,
                                                 const float* __restrict__ W0,
                                                 float* __restrict__ p0, int n) {
    __shared__ float Ws[800];
    for (int idx = threadIdx.x; idx < 800; idx += 256) Ws[idx] = W0[idx];
    __syncthreads();
    int gid = blockIdx.x * blockDim.x + threadIdx.x;
    if (gid < n * 200) {
        int v = gid / 200, c = gid - v * 200;
        float4 xv = ((const float4*)px)[v];
        p0[gid] = xv.x * Ws[c] + xv.y * Ws[200 + c] + xv.z * Ws[400 + c] + xv.w * Ws[600 + c];
    }
}

// ================= main GEMM: T = leaky(P + bprev) @ W   (M x 200)@(200 x 200) =================
// 80-row x 200-col tile per block, 8x8 register blocking, 250/256 active threads.
__global__ __launch_bounds__(256) void k_gemm200(const float* __restrict__ P,
                                                 const float* __restrict__ bprev,
                                                 const float* __restrict__ W,
                                                 float* __restrict__ T, int n) {
    __shared__ float As[8][80];
    __shared__ float Ws[8][200];
    const int tid = threadIdx.x;
    const int row0 = blockIdx.x * 80;
    const int rg = tid / 25;   // 0..9 for active threads
    const int cg = tid % 25;   // 0..24
    const bool active = tid < 250;
    float acc[8][8];
#pragma unroll
    for (int i = 0; i < 8; ++i)
#pragma unroll
        for (int j = 0; j < 8; ++j) acc[i][j] = 0.0f;

    for (int k0 = 0; k0 < 200; k0 += 8) {
        for (int idx = tid; idx < 640; idx += 256) {
            int r = idx >> 3, kk = idx & 7;
            int row = row0 + r;
            float v = 0.0f;
            if (row < n) {
                v = P[row * 200 + k0 + kk] + bprev[k0 + kk];
                v = LEAKY(v);
            }
            As[kk][r] = v;
        }
        for (int idx = tid; idx < 1600; idx += 256) {
            int kk = idx / 200, c = idx - kk * 200;
            Ws[kk][c] = W[(k0 + kk) * 200 + c];
        }
        __syncthreads();
        if (active) {
#pragma unroll
            for (int kk = 0; kk < 8; ++kk) {
                float a[8], w[8];
                *(float4*)&a[0] = *(const float4*)&As[kk][rg * 8];
                *(float4*)&a[4] = *(const float4*)&As[kk][rg * 8 + 4];
                *(float4*)&w[0] = *(const float4*)&Ws[kk][cg * 8];
                *(float4*)&w[4] = *(const float4*)&Ws[kk][cg * 8 + 4];
#pragma unroll
                for (int i = 0; i < 8; ++i)
#pragma unroll
                    for (int j = 0; j < 8; ++j) acc[i][j] += a[i] * w[j];
            }
        }
        __syncthreads();
    }
    if (active) {
#pragma unroll
        for (int i = 0; i < 8; ++i) {
            int r = row0 + rg * 8 + i;
            if (r < n) {
                float4 o0 = make_float4(acc[i][0], acc[i][1], acc[i][2], acc[i][3]);
                float4 o1 = make_float4(acc[i][4], acc[i][5], acc[i][6], acc[i][7]);
                *(float4*)&T[r * 200 + cg * 8] = o0;
                *(float4*)&T[r * 200 + cg * 8 + 4] = o1;
            }
        }
    }
}

// ================= propagation (200-wide) via CSR gather =================
// p[v] = dinv[v]^2 * t[v] + sum_{e: dst=v} w[e] * t[src[e]]
// thread = (node, float4 chunk); 50 chunks per node.
__global__ __launch_bounds__(256) void k_gather200(const float* __restrict__ t,
                                                   const float* __restrict__ dinv,
                                                   const int* __restrict__ rowptr,
                                                   const int* __restrict__ col,
                                                   const float* __restrict__ wgt,
                                                   float* __restrict__ p, int n) {
    int gid = blockIdx.x * blockDim.x + threadIdx.x;
    if (gid >= n * 50) return;
    int v = gid / 50, c4 = gid - v * 50;
    float w0 = dinv[v]; w0 *= w0;
    float4 tv = ((const float4*)t)[gid];
    float4 acc = make_float4(tv.x * w0, tv.y * w0, tv.z * w0, tv.w * w0);
    int lo = rowptr[v], hi = rowptr[v + 1];
    for (int j = lo; j < hi; ++j) {
        int s = col[j];          // same address across the node's 50 threads -> broadcast
        float w = wgt[j];
        float4 sv = ((const float4*)t)[s * 50 + c4];  // coalesced 800B row read
        acc.x += sv.x * w; acc.y += sv.y * w; acc.z += sv.z * w; acc.w += sv.w * w;
    }
    ((float4*)p)[gid] = acc;
}

// ================= pooling: per-graph mean of leaky(p3 + b3) =================
__global__ __launch_bounds__(256) void k_pool(const float* __restrict__ p3,
                                              const float* __restrict__ b3,
                                              const int* __restrict__ batch, int n_nodes,
                                              float* __restrict__ pooled) {
    __shared__ int sb[2];
    int g = blockIdx.x;
    if (threadIdx.x == 0) {
        int lo = 0, hi = n_nodes;
        while (lo < hi) { int m = (lo + hi) >> 1; if (batch[m] < g) lo = m + 1; else hi = m; }
        sb[0] = lo;
        int lo2 = lo, hi2 = n_nodes;
        while (lo2 < hi2) { int m = (lo2 + hi2) >> 1; if (batch[m] < g + 1) lo2 = m + 1; else hi2 = m; }
        sb[1] = lo2;
    }
    __syncthreads();
    int lo = sb[0], hi = sb[1];
    int c = threadIdx.x;
    if (c < 200) {
        float bc = b3[c];
        float s = 0.0f;
        for (int nidx = lo; nidx < hi; ++nidx) {
            float v = p3[nidx * 200 + c] + bc;
            s += LEAKY(v);
        }
        float cnt = (float)(hi - lo);
        pooled[g * 200 + c] = s / fmaxf(cnt, 1.0f);
    }
}

// ================= head MLP =================
__global__ __launch_bounds__(128) void k_mlp(const float* __restrict__ pooled,
                                             const float* __restrict__ xs,
                                             const float* __restrict__ Wl1,
                                             const float* __restrict__ bl1,
                                             const float* __restrict__ Wl2,
                                             const float* __restrict__ bl2,
                                             float* __restrict__ out) {
    __shared__ float grow[204];
    __shared__ float partial[2];
    int g = blockIdx.x;
    int t = threadIdx.x;
    for (int idx = t; idx < 200; idx += 128) grow[idx] = pooled[g * 200 + idx];
    if (t < 4) grow[200 + t] = xs[g * 4 + t];
    __syncthreads();
    float s = bl1[t];
    for (int k = 0; k < 204; ++k) s += grow[k] * Wl1[k * 128 + t];
    s = LEAKY(s);
    float v = s * Wl2[t];
    for (int off = 32; off > 0; off >>= 1) v += __shfl_down(v, off, 64);
    if ((t & 63) == 0) partial[t >> 6] = v;
    __syncthreads();
    if (t == 0) out[g] = partial[0] + partial[1] + bl2[0];
}

extern "C" void kernel_launch(void* const* d_in, const int* in_sizes, int n_in,
                              void* d_out, int out_size, void* d_ws, size_t ws_size,
                              hipStream_t stream) {
    const float* x    = (const float*)d_in[0];
    const int*   ei   = (const int*)d_in[1];
    const float* xs   = (const float*)d_in[2];
    const int*   batch= (const int*)d_in[3];
    const float* W0   = (const float*)d_in[4];
    const float* b0   = (const float*)d_in[5];
    const float* W1   = (const float*)d_in[6];
    const float* b1   = (const float*)d_in[7];
    const float* W2   = (const float*)d_in[8];
    const float* b2   = (const float*)d_in[9];
    const float* W3   = (const float*)d_in[10];
    const float* b3   = (const float*)d_in[11];
    const float* Wl1  = (const float*)d_in[12];
    const float* bl1  = (const float*)d_in[13];
    const float* Wl2  = (const float*)d_in[14];
    const float* bl2  = (const float*)d_in[15];
    float* out = (float*)d_out;

    const int N = in_sizes[0] / 4;   // 50000 nodes
    const int E = in_sizes[1] / 2;   // 400000 edges
    const int G = in_sizes[2] / 4;   // 500 graphs

    char* ws = (char*)d_ws;
    size_t off = 0;
    auto alloc = [&](size_t bytes) { void* p = ws + off; off += (bytes + 255) & ~size_t(255); return p; };
    float* buf0   = (float*)alloc((size_t)N * 200 * sizeof(float));  // 40 MB
    float* buf1   = (float*)alloc((size_t)N * 200 * sizeof(float));  // 40 MB
    float* dinv   = (float*)alloc((size_t)N * sizeof(float));
    float* px     = (float*)alloc((size_t)N * 4 * sizeof(float));
    float* pooled = (float*)alloc((size_t)G * 200 * sizeof(float));
    int*   cnt    = (int*)alloc((size_t)N * sizeof(int));
    int*   fillc  = (int*)alloc((size_t)N * sizeof(int));
    int*   rowptr = (int*)alloc(((size_t)N + 1) * sizeof(int));
    int*   col    = (int*)alloc((size_t)E * sizeof(int));
    float* wgt    = (float*)alloc((size_t)E * sizeof(float));

    const int B = 256;
    // CSR build (by destination) + norms
    k_zero2<<<(N + B - 1) / B, B, 0, stream>>>(cnt, fillc, N);
    k_count<<<(E + B - 1) / B, B, 0, stream>>>(ei, cnt, E);
    k_scan<<<1, 1024, 0, stream>>>(cnt, rowptr, N);
    k_dinv<<<(N + B - 1) / B, B, 0, stream>>>(cnt, dinv, N);
    k_fill<<<(E + B - 1) / B, B, 0, stream>>>(ei, dinv, rowptr, fillc, col, wgt, E);

    // layer 0: gather x (4-wide) then 4->200 GEMM
    k_gather4<<<(N + B - 1) / B, B, 0, stream>>>(x, dinv, rowptr, col, wgt, px, N);
    k_gemm_l0<<<(N * 200 + B - 1) / B, B, 0, stream>>>(px, W0, buf0, N);

    // layers 1..3: GEMM (bias+leaky of prev layer fused into A load) then gather-propagate
    const float* Wcur[3]  = {W1, W2, W3};
    const float* bprev[3] = {b0, b1, b2};
    for (int L = 0; L < 3; ++L) {
        k_gemm200<<<(N + 79) / 80, 256, 0, stream>>>(buf0, bprev[L], Wcur[L], buf1, N);
        k_gather200<<<(N * 50 + B - 1) / B, B, 0, stream>>>(buf1, dinv, rowptr, col, wgt, buf0, N);
    }

    // pool (applies leaky(p3 + b3)) + head MLP
    k_pool<<<G, 256, 0, stream>>>(buf0, b3, batch, N, pooled);
    k_mlp<<<G, 128, 0, stream>>>(pooled, xs, Wl1, bl1, Wl2, bl2, out);
}

// Round 3
// 822.225 us; speedup vs baseline: 5.1668x; 1.2767x over previous
//
#include <hip/hip_runtime.h>
#include <math.h>

#define LEAKY(v) ((v) > 0.0f ? (v) : 0.01f * (v))

// ================= CSR build =================
__global__ void k_zero2(int* __restrict__ cnt, int* __restrict__ fill, int n) {
    int i = blockIdx.x * blockDim.x + threadIdx.x;
    if (i < n) { cnt[i] = 0; fill[i] = 0; }
}

__global__ void k_count(const int* __restrict__ ei, int* __restrict__ cnt, int E) {
    int e = blockIdx.x * blockDim.x + threadIdx.x;
    if (e < E) atomicAdd(&cnt[ei[E + e]], 1);
}

// exclusive scan of cnt[0..n-1] -> rowptr[0..n] (single 1024-thread block)
__global__ __launch_bounds__(1024) void k_scan(const int* __restrict__ cnt,
                                               int* __restrict__ rowptr, int n) {
    __shared__ int ssum[1024];
    const int t = threadIdx.x;
    const int chunk = (n + 1023) / 1024;
    const int lo = t * chunk;
    const int hi = min(lo + chunk, n);
    int s = 0;
    for (int i = lo; i < hi; ++i) s += cnt[i];
    ssum[t] = s;
    __syncthreads();
    for (int off = 1; off < 1024; off <<= 1) {
        int v = (t >= off) ? ssum[t - off] : 0;
        __syncthreads();
        ssum[t] += v;
        __syncthreads();
    }
    int base = (t == 0) ? 0 : ssum[t - 1];
    for (int i = lo; i < hi; ++i) { rowptr[i] = base; base += cnt[i]; }
    if (hi == n) rowptr[n] = base;
}

__global__ void k_dinv(const int* __restrict__ cnt, float* __restrict__ dinv, int n) {
    int i = blockIdx.x * blockDim.x + threadIdx.x;
    if (i < n) dinv[i] = rsqrtf(1.0f + (float)cnt[i]);  // +1 self-loop
}

__global__ void k_fill(const int* __restrict__ ei, const float* __restrict__ dinv,
                       const int* __restrict__ rowptr, int* __restrict__ fill,
                       int* __restrict__ col, float* __restrict__ wgt, int E) {
    int e = blockIdx.x * blockDim.x + threadIdx.x;
    if (e < E) {
        int s = ei[e], d = ei[E + e];
        int pos = rowptr[d] + atomicAdd(&fill[d], 1);
        col[pos] = s;
        wgt[pos] = dinv[s] * dinv[d];
    }
}

// ================= layer-0: gather x (4-wide), then 4->200 GEMM =================
__global__ void k_gather4(const float* __restrict__ x, const float* __restrict__ dinv,
                          const int* __restrict__ rowptr, const int* __restrict__ col,
                          const float* __restrict__ wgt, float* __restrict__ px, int n) {
    int v = blockIdx.x * blockDim.x + threadIdx.x;
    if (v >= n) return;
    float w0 = dinv[v]; w0 *= w0;
    float4 xv = ((const float4*)x)[v];
    float4 acc = make_float4(xv.x * w0, xv.y * w0, xv.z * w0, xv.w * w0);
    int lo = rowptr[v], hi = rowptr[v + 1];
    for (int j = lo; j < hi; ++j) {
        int s = col[j]; float w = wgt[j];
        float4 sv = ((const float4*)x)[s];
        acc.x += sv.x * w; acc.y += sv.y * w; acc.z += sv.z * w; acc.w += sv.w * w;
    }
    ((float4*)px)[v] = acc;
}

// p0 = px @ W0  (n x 4)@(4 x 200). Swizzled LDS for W0 (bank-conflict-free float4 reads).
__global__ __launch_bounds__(256) void k_gemm_l0(const float* __restrict__ px,
                                                 const float* __restrict__ W0,
                                                 float* __restrict__ p0, int n) {
    __shared__ float Ws[4][224];  // c -> c + (c>>5)*4
    for (int idx = threadIdx.x; idx < 800; idx += 256) {
        int k = idx / 200, c = idx - k * 200;
        Ws[k][c + ((c >> 5) << 2)] = W0[idx];
    }
    __syncthreads();
    int gid = blockIdx.x * blockDim.x + threadIdx.x;  // over n*50 float4 outputs
    if (gid < n * 50) {
        int v = gid / 50, c4 = gid - v * 50;
        int c = c4 * 4, sc = c + ((c >> 5) << 2);
        float4 xv = ((const float4*)px)[v];
        float4 w0 = *(const float4*)&Ws[0][sc];
        float4 w1 = *(const float4*)&Ws[1][sc];
        float4 w2 = *(const float4*)&Ws[2][sc];
        float4 w3 = *(const float4*)&Ws[3][sc];
        float4 o;
        o.x = xv.x * w0.x + xv.y * w1.x + xv.z * w2.x + xv.w * w3.x;
        o.y = xv.x * w0.y + xv.y * w1.y + xv.z * w2.y + xv.w * w3.y;
        o.z = xv.x * w0.z + xv.y * w1.z + xv.z * w2.z + xv.w * w3.z;
        o.w = xv.x * w0.w + xv.y * w1.w + xv.z * w2.w + xv.w * w3.w;
        ((float4*)p0)[gid] = o;
    }
}

// ================= main GEMM: T = leaky(P + bprev) @ W  (M x 200)@(200 x 200) =================
// 80x200 tile, 250/256 threads, 8x8 acc split 4+4 rows/cols, BK=25, swizzled Ws.
__global__ __launch_bounds__(256) void k_gemm200(const float* __restrict__ P,
                                                 const float* __restrict__ bprev,
                                                 const float* __restrict__ W,
                                                 float* __restrict__ T, int n) {
    __shared__ float As[25][84];   // stride 84: staging-write conflicts ~4-way max
    __shared__ float Ws[25][224];  // swizzle c -> c + (c>>5)*4: reads <=2-way
    const int tid = threadIdx.x;
    const int row0 = blockIdx.x * 80;
    const int rg = tid / 25;   // 0..9 active
    const int cg = tid % 25;   // 0..24
    const bool active = tid < 250;
    const int c0 = cg * 4, c1 = 100 + cg * 4;
    const int sw0 = c0 + ((c0 >> 5) << 2);
    const int sw1 = c1 + ((c1 >> 5) << 2);
    float acc[8][8];
#pragma unroll
    for (int i = 0; i < 8; ++i)
#pragma unroll
        for (int j = 0; j < 8; ++j) acc[i][j] = 0.0f;

    for (int k0 = 0; k0 < 200; k0 += 25) {
        // stage A (80 rows x 25 k), fused bias+leaky, transposed -> As[kk][r]
        for (int idx = tid; idx < 2000; idx += 256) {
            int r = idx / 25, kk = idx - r * 25;
            int row = row0 + r;
            float v = 0.0f;
            if (row < n) {
                v = P[row * 200 + k0 + kk] + bprev[k0 + kk];
                v = LEAKY(v);
            }
            As[kk][r] = v;
        }
        // stage W (25 k x 200 cols), swizzled
        for (int idx = tid; idx < 5000; idx += 256) {
            int kk = idx / 200, c = idx - kk * 200;
            Ws[kk][c + ((c >> 5) << 2)] = W[(k0 + kk) * 200 + c];
        }
        __syncthreads();
        if (active) {
#pragma unroll
            for (int kk = 0; kk < 25; ++kk) {
                float4 a0 = *(const float4*)&As[kk][rg * 4];
                float4 a1 = *(const float4*)&As[kk][40 + rg * 4];
                float4 w0 = *(const float4*)&Ws[kk][sw0];
                float4 w1 = *(const float4*)&Ws[kk][sw1];
                float a[8] = {a0.x, a0.y, a0.z, a0.w, a1.x, a1.y, a1.z, a1.w};
                float w[8] = {w0.x, w0.y, w0.z, w0.w, w1.x, w1.y, w1.z, w1.w};
#pragma unroll
                for (int i = 0; i < 8; ++i)
#pragma unroll
                    for (int j = 0; j < 8; ++j) acc[i][j] += a[i] * w[j];
            }
        }
        __syncthreads();
    }
    if (active) {
#pragma unroll
        for (int i = 0; i < 8; ++i) {
            int r = row0 + ((i < 4) ? (rg * 4 + i) : (40 + rg * 4 + i - 4));
            if (r < n) {
                float4 o0 = make_float4(acc[i][0], acc[i][1], acc[i][2], acc[i][3]);
                float4 o1 = make_float4(acc[i][4], acc[i][5], acc[i][6], acc[i][7]);
                *(float4*)&T[r * 200 + c0] = o0;
                *(float4*)&T[r * 200 + c1] = o1;
            }
        }
    }
}

// ================= propagation (200-wide) via CSR gather =================
// thread = (node, 8-float chunk): 25 threads per node.
__global__ __launch_bounds__(256) void k_gather200(const float* __restrict__ t,
                                                   const float* __restrict__ dinv,
                                                   const int* __restrict__ rowptr,
                                                   const int* __restrict__ col,
                                                   const float* __restrict__ wgt,
                                                   float* __restrict__ p, int n) {
    int gid = blockIdx.x * blockDim.x + threadIdx.x;
    if (gid >= n * 25) return;
    int v = gid / 25, c8 = gid - v * 25;
    const float4* tp = (const float4*)t;
    int idx4 = v * 50 + c8 * 2;
    float w0 = dinv[v]; w0 *= w0;
    float4 t0 = tp[idx4], t1 = tp[idx4 + 1];
    float4 acc0 = make_float4(t0.x * w0, t0.y * w0, t0.z * w0, t0.w * w0);
    float4 acc1 = make_float4(t1.x * w0, t1.y * w0, t1.z * w0, t1.w * w0);
    int lo = rowptr[v], hi = rowptr[v + 1];
    for (int j = lo; j < hi; ++j) {
        int s = col[j];           // broadcast across the node's 25 lanes
        float w = wgt[j];
        int si = s * 50 + c8 * 2;
        float4 s0 = tp[si], s1 = tp[si + 1];  // coalesced row read
        acc0.x += s0.x * w; acc0.y += s0.y * w; acc0.z += s0.z * w; acc0.w += s0.w * w;
        acc1.x += s1.x * w; acc1.y += s1.y * w; acc1.z += s1.z * w; acc1.w += s1.w * w;
    }
    float4* pp = (float4*)p;
    pp[idx4] = acc0;
    pp[idx4 + 1] = acc1;
}

// ================= pooling: per-graph mean of leaky(p3 + b3) =================
__global__ __launch_bounds__(256) void k_pool(const float* __restrict__ p3,
                                              const float* __restrict__ b3,
                                              const int* __restrict__ batch, int n_nodes,
                                              float* __restrict__ pooled) {
    __shared__ int sb[2];
    int g = blockIdx.x;
    if (threadIdx.x == 0) {
        int lo = 0, hi = n_nodes;
        while (lo < hi) { int m = (lo + hi) >> 1; if (batch[m] < g) lo = m + 1; else hi = m; }
        sb[0] = lo;
        int lo2 = lo, hi2 = n_nodes;
        while (lo2 < hi2) { int m = (lo2 + hi2) >> 1; if (batch[m] < g + 1) lo2 = m + 1; else hi2 = m; }
        sb[1] = lo2;
    }
    __syncthreads();
    int lo = sb[0], hi = sb[1];
    int c = threadIdx.x;
    if (c < 200) {
        float bc = b3[c];
        float s = 0.0f;
        for (int nidx = lo; nidx < hi; ++nidx) {
            float v = p3[nidx * 200 + c] + bc;
            s += LEAKY(v);
        }
        float cnt = (float)(hi - lo);
        pooled[g * 200 + c] = s / fmaxf(cnt, 1.0f);
    }
}

// ================= head MLP =================
__global__ __launch_bounds__(128) void k_mlp(const float* __restrict__ pooled,
                                             const float* __restrict__ xs,
                                             const float* __restrict__ Wl1,
                                             const float* __restrict__ bl1,
                                             const float* __restrict__ Wl2,
                                             const float* __restrict__ bl2,
                                             float* __restrict__ out) {
    __shared__ float grow[204];
    __shared__ float partial[2];
    int g = blockIdx.x;
    int t = threadIdx.x;
    for (int idx = t; idx < 200; idx += 128) grow[idx] = pooled[g * 200 + idx];
    if (t < 4) grow[200 + t] = xs[g * 4 + t];
    __syncthreads();
    float s = bl1[t];
    for (int k = 0; k < 204; ++k) s += grow[k] * Wl1[k * 128 + t];
    s = LEAKY(s);
    float v = s * Wl2[t];
    for (int off = 32; off > 0; off >>= 1) v += __shfl_down(v, off, 64);
    if ((t & 63) == 0) partial[t >> 6] = v;
    __syncthreads();
    if (t == 0) out[g] = partial[0] + partial[1] + bl2[0];
}

extern "C" void kernel_launch(void* const* d_in, const int* in_sizes, int n_in,
                              void* d_out, int out_size, void* d_ws, size_t ws_size,
                              hipStream_t stream) {
    const float* x    = (const float*)d_in[0];
    const int*   ei   = (const int*)d_in[1];
    const float* xs   = (const float*)d_in[2];
    const int*   batch= (const int*)d_in[3];
    const float* W0   = (const float*)d_in[4];
    const float* b0   = (const float*)d_in[5];
    const float* W1   = (const float*)d_in[6];
    const float* b1   = (const float*)d_in[7];
    const float* W2   = (const float*)d_in[8];
    const float* b2   = (const float*)d_in[9];
    const float* W3   = (const float*)d_in[10];
    const float* b3   = (const float*)d_in[11];
    const float* Wl1  = (const float*)d_in[12];
    const float* bl1  = (const float*)d_in[13];
    const float* Wl2  = (const float*)d_in[14];
    const float* bl2  = (const float*)d_in[15];
    float* out = (float*)d_out;

    const int N = in_sizes[0] / 4;   // 50000 nodes
    const int E = in_sizes[1] / 2;   // 400000 edges
    const int G = in_sizes[2] / 4;   // 500 graphs

    char* ws = (char*)d_ws;
    size_t off = 0;
    auto alloc = [&](size_t bytes) { void* p = ws + off; off += (bytes + 255) & ~size_t(255); return p; };
    float* buf0   = (float*)alloc((size_t)N * 200 * sizeof(float));
    float* buf1   = (float*)alloc((size_t)N * 200 * sizeof(float));
    float* dinv   = (float*)alloc((size_t)N * sizeof(float));
    float* px     = (float*)alloc((size_t)N * 4 * sizeof(float));
    float* pooled = (float*)alloc((size_t)G * 200 * sizeof(float));
    int*   cnt    = (int*)alloc((size_t)N * sizeof(int));
    int*   fillc  = (int*)alloc((size_t)N * sizeof(int));
    int*   rowptr = (int*)alloc(((size_t)N + 1) * sizeof(int));
    int*   col    = (int*)alloc((size_t)E * sizeof(int));
    float* wgt    = (float*)alloc((size_t)E * sizeof(float));

    const int B = 256;
    // CSR build (by destination) + norms
    k_zero2<<<(N + B - 1) / B, B, 0, stream>>>(cnt, fillc, N);
    k_count<<<(E + B - 1) / B, B, 0, stream>>>(ei, cnt, E);
    k_scan<<<1, 1024, 0, stream>>>(cnt, rowptr, N);
    k_dinv<<<(N + B - 1) / B, B, 0, stream>>>(cnt, dinv, N);
    k_fill<<<(E + B - 1) / B, B, 0, stream>>>(ei, dinv, rowptr, fillc, col, wgt, E);

    // layer 0: gather x (4-wide) then 4->200 GEMM
    k_gather4<<<(N + B - 1) / B, B, 0, stream>>>(x, dinv, rowptr, col, wgt, px, N);
    k_gemm_l0<<<(N * 50 + B - 1) / B, B, 0, stream>>>(px, W0, buf0, N);

    // layers 1..3: GEMM (bias+leaky fused) then gather-propagate
    const float* Wcur[3]  = {W1, W2, W3};
    const float* bprev[3] = {b0, b1, b2};
    for (int L = 0; L < 3; ++L) {
        k_gemm200<<<(N + 79) / 80, 256, 0, stream>>>(buf0, bprev[L], Wcur[L], buf1, N);
        k_gather200<<<(N * 25 + B - 1) / B, B, 0, stream>>>(buf1, dinv, rowptr, col, wgt, buf0, N);
    }

    // pool (applies leaky(p3 + b3)) + head MLP
    k_pool<<<G, 256, 0, stream>>>(buf0, b3, batch, N, pooled);
    k_mlp<<<G, 128, 0, stream>>>(pooled, xs, Wl1, bl1, Wl2, bl2, out);
}

// Round 4
// 718.762 us; speedup vs baseline: 5.9106x; 1.1439x over previous
//
#include <hip/hip_runtime.h>
#include <math.h>

#define LEAKY(v) ((v) > 0.0f ? (v) : 0.01f * (v))

// ================= CSR build =================
__global__ void k_zero2(int* __restrict__ cnt, int* __restrict__ fill, int n) {
    int i = blockIdx.x * blockDim.x + threadIdx.x;
    if (i < n) { cnt[i] = 0; fill[i] = 0; }
}

__global__ void k_count(const int* __restrict__ ei, int* __restrict__ cnt, int E) {
    int e = blockIdx.x * blockDim.x + threadIdx.x;
    if (e < E) atomicAdd(&cnt[ei[E + e]], 1);
}

// exclusive scan of cnt[0..n-1] -> rowptr[0..n] (single 1024-thread block)
__global__ __launch_bounds__(1024) void k_scan(const int* __restrict__ cnt,
                                               int* __restrict__ rowptr, int n) {
    __shared__ int ssum[1024];
    const int t = threadIdx.x;
    const int chunk = (n + 1023) / 1024;
    const int lo = t * chunk;
    const int hi = min(lo + chunk, n);
    int s = 0;
    for (int i = lo; i < hi; ++i) s += cnt[i];
    ssum[t] = s;
    __syncthreads();
    for (int off = 1; off < 1024; off <<= 1) {
        int v = (t >= off) ? ssum[t - off] : 0;
        __syncthreads();
        ssum[t] += v;
        __syncthreads();
    }
    int base = (t == 0) ? 0 : ssum[t - 1];
    for (int i = lo; i < hi; ++i) { rowptr[i] = base; base += cnt[i]; }
    if (hi == n) rowptr[n] = base;
}

__global__ void k_dinv(const int* __restrict__ cnt, float* __restrict__ dinv, int n) {
    int i = blockIdx.x * blockDim.x + threadIdx.x;
    if (i < n) dinv[i] = rsqrtf(1.0f + (float)cnt[i]);  // +1 self-loop
}

__global__ void k_fill(const int* __restrict__ ei, const float* __restrict__ dinv,
                       const int* __restrict__ rowptr, int* __restrict__ fill,
                       int* __restrict__ col, float* __restrict__ wgt, int E) {
    int e = blockIdx.x * blockDim.x + threadIdx.x;
    if (e < E) {
        int s = ei[e], d = ei[E + e];
        int pos = rowptr[d] + atomicAdd(&fill[d], 1);
        col[pos] = s;
        wgt[pos] = dinv[s] * dinv[d];
    }
}

// ================= layer-0: gather x (4-wide), then 4->200 GEMM =================
__global__ void k_gather4(const float* __restrict__ x, const float* __restrict__ dinv,
                          const int* __restrict__ rowptr, const int* __restrict__ col,
                          const float* __restrict__ wgt, float* __restrict__ px, int n) {
    int v = blockIdx.x * blockDim.x + threadIdx.x;
    if (v >= n) return;
    float w0 = dinv[v]; w0 *= w0;
    float4 xv = ((const float4*)x)[v];
    float4 acc = make_float4(xv.x * w0, xv.y * w0, xv.z * w0, xv.w * w0);
    int lo = rowptr[v], hi = rowptr[v + 1];
    for (int j = lo; j < hi; ++j) {
        int s = col[j]; float w = wgt[j];
        float4 sv = ((const float4*)x)[s];
        acc.x += sv.x * w; acc.y += sv.y * w; acc.z += sv.z * w; acc.w += sv.w * w;
    }
    ((float4*)px)[v] = acc;
}

// p0 = px @ W0  (n x 4)@(4 x 200). Swizzled LDS for W0.
__global__ __launch_bounds__(256) void k_gemm_l0(const float* __restrict__ px,
                                                 const float* __restrict__ W0,
                                                 float* __restrict__ p0, int n) {
    __shared__ float Ws[4][224];  // c -> c + (c>>5)*4
    for (int idx = threadIdx.x; idx < 800; idx += 256) {
        int k = idx / 200, c = idx - k * 200;
        Ws[k][c + ((c >> 5) << 2)] = W0[idx];
    }
    __syncthreads();
    int gid = blockIdx.x * blockDim.x + threadIdx.x;  // over n*50 float4 outputs
    if (gid < n * 50) {
        int v = gid / 50, c4 = gid - v * 50;
        int c = c4 * 4, sc = c + ((c >> 5) << 2);
        float4 xv = ((const float4*)px)[v];
        float4 w0 = *(const float4*)&Ws[0][sc];
        float4 w1 = *(const float4*)&Ws[1][sc];
        float4 w2 = *(const float4*)&Ws[2][sc];
        float4 w3 = *(const float4*)&Ws[3][sc];
        float4 o;
        o.x = xv.x * w0.x + xv.y * w1.x + xv.z * w2.x + xv.w * w3.x;
        o.y = xv.x * w0.y + xv.y * w1.y + xv.z * w2.y + xv.w * w3.y;
        o.z = xv.x * w0.z + xv.y * w1.z + xv.z * w2.z + xv.w * w3.z;
        o.w = xv.x * w0.w + xv.y * w1.w + xv.z * w2.w + xv.w * w3.w;
        ((float4*)p0)[gid] = o;
    }
}

// ================= main GEMM: T = leaky(P + bprev) @ W  (M x 200)@(200 x 200) =================
// 80x200 tile, 250/256 active, 8x8 acc, BK=40 (5 panels).
// Lane map rg=tid%10, cg=tid/10: per-wave LDS reads are broadcast-dominated
// (~10 distinct A addrs, ~7 distinct W addrs) -> near-zero bank conflicts.
__global__ __launch_bounds__(256) void k_gemm200(const float* __restrict__ P,
                                                 const float* __restrict__ bprev,
                                                 const float* __restrict__ W,
                                                 float* __restrict__ T, int n) {
    __shared__ float As[40][84];   // [kk][row], stride 84 (16B-aligned rows)
    __shared__ float Ws[40][224];  // swizzle c -> c + (c>>5)*4
    const int tid = threadIdx.x;
    const int row0 = blockIdx.x * 80;
    const int rg = tid % 10;
    const int cg = tid / 10;       // 0..24 active
    const bool active = tid < 250;
    const int c0 = cg * 4, c1 = 100 + cg * 4;
    const int sw0 = c0 + ((c0 >> 5) << 2);
    const int sw1 = c1 + ((c1 >> 5) << 2);
    float acc[8][8];
#pragma unroll
    for (int i = 0; i < 8; ++i)
#pragma unroll
        for (int j = 0; j < 8; ++j) acc[i][j] = 0.0f;

    for (int k0 = 0; k0 < 200; k0 += 40) {
        // stage A: 80 rows x 40 k = 800 float4 loads, fused bias+leaky, transpose to As[kk][r]
        for (int f = tid; f < 800; f += 256) {
            int r = f / 10, j = f - r * 10;
            int row = row0 + r;
            float4 v = make_float4(0.f, 0.f, 0.f, 0.f);
            if (row < n) {
                float4 pv = *(const float4*)&P[row * 200 + k0 + j * 4];
                float4 bb = *(const float4*)&bprev[k0 + j * 4];
                v.x = LEAKY(pv.x + bb.x);
                v.y = LEAKY(pv.y + bb.y);
                v.z = LEAKY(pv.z + bb.z);
                v.w = LEAKY(pv.w + bb.w);
            }
            As[j * 4 + 0][r] = v.x;
            As[j * 4 + 1][r] = v.y;
            As[j * 4 + 2][r] = v.z;
            As[j * 4 + 3][r] = v.w;
        }
        // stage W: 40 k x 200 cols = 2000 float4, swizzled, float4 writes
        for (int f = tid; f < 2000; f += 256) {
            int kk = f / 50, c4 = f - kk * 50;
            int c = c4 * 4;
            float4 wv = *(const float4*)&W[(k0 + kk) * 200 + c];
            *(float4*)&Ws[kk][c + ((c >> 5) << 2)] = wv;
        }
        __syncthreads();
        if (active) {
#pragma unroll 8
            for (int kk = 0; kk < 40; ++kk) {
                float4 a0 = *(const float4*)&As[kk][rg * 4];
                float4 a1 = *(const float4*)&As[kk][40 + rg * 4];
                float4 w0 = *(const float4*)&Ws[kk][sw0];
                float4 w1 = *(const float4*)&Ws[kk][sw1];
                float a[8] = {a0.x, a0.y, a0.z, a0.w, a1.x, a1.y, a1.z, a1.w};
                float w[8] = {w0.x, w0.y, w0.z, w0.w, w1.x, w1.y, w1.z, w1.w};
#pragma unroll
                for (int i = 0; i < 8; ++i)
#pragma unroll
                    for (int j = 0; j < 8; ++j) acc[i][j] += a[i] * w[j];
            }
        }
        __syncthreads();
    }
    if (active) {
#pragma unroll
        for (int i = 0; i < 8; ++i) {
            int r = row0 + ((i < 4) ? (rg * 4 + i) : (40 + rg * 4 + i - 4));
            if (r < n) {
                float4 o0 = make_float4(acc[i][0], acc[i][1], acc[i][2], acc[i][3]);
                float4 o1 = make_float4(acc[i][4], acc[i][5], acc[i][6], acc[i][7]);
                *(float4*)&T[r * 200 + c0] = o0;
                *(float4*)&T[r * 200 + c1] = o1;
            }
        }
    }
}

// ================= propagation (200-wide) via CSR gather =================
// thread = (node, float4 chunk): 50 threads per node for max TLP.
__global__ __launch_bounds__(256) void k_gather200(const float* __restrict__ t,
                                                   const float* __restrict__ dinv,
                                                   const int* __restrict__ rowptr,
                                                   const int* __restrict__ col,
                                                   const float* __restrict__ wgt,
                                                   float* __restrict__ p, int n) {
    int gid = blockIdx.x * blockDim.x + threadIdx.x;
    if (gid >= n * 50) return;
    int v = gid / 50, c4 = gid - v * 50;
    const float4* tp = (const float4*)t;
    float w0 = dinv[v]; w0 *= w0;
    float4 tv = tp[gid];
    float4 acc = make_float4(tv.x * w0, tv.y * w0, tv.z * w0, tv.w * w0);
    int lo = rowptr[v], hi = rowptr[v + 1];
    for (int j = lo; j < hi; ++j) {
        int s = col[j];           // broadcast across the node's 50 lanes
        float w = wgt[j];
        float4 sv = tp[s * 50 + c4];  // coalesced row read
        acc.x += sv.x * w; acc.y += sv.y * w; acc.z += sv.z * w; acc.w += sv.w * w;
    }
    ((float4*)p)[gid] = acc;
}

// ================= pooling: per-graph mean of leaky(p3 + b3) =================
__global__ __launch_bounds__(256) void k_pool(const float* __restrict__ p3,
                                              const float* __restrict__ b3,
                                              const int* __restrict__ batch, int n_nodes,
                                              float* __restrict__ pooled) {
    __shared__ int sb[2];
    int g = blockIdx.x;
    if (threadIdx.x == 0) {
        int lo = 0, hi = n_nodes;
        while (lo < hi) { int m = (lo + hi) >> 1; if (batch[m] < g) lo = m + 1; else hi = m; }
        sb[0] = lo;
        int lo2 = lo, hi2 = n_nodes;
        while (lo2 < hi2) { int m = (lo2 + hi2) >> 1; if (batch[m] < g + 1) lo2 = m + 1; else hi2 = m; }
        sb[1] = lo2;
    }
    __syncthreads();
    int lo = sb[0], hi = sb[1];
    int c = threadIdx.x;
    if (c < 200) {
        float bc = b3[c];
        float s = 0.0f;
        for (int nidx = lo; nidx < hi; ++nidx) {
            float v = p3[nidx * 200 + c] + bc;
            s += LEAKY(v);
        }
        float cnt = (float)(hi - lo);
        pooled[g * 200 + c] = s / fmaxf(cnt, 1.0f);
    }
}

// ================= head MLP =================
__global__ __launch_bounds__(128) void k_mlp(const float* __restrict__ pooled,
                                             const float* __restrict__ xs,
                                             const float* __restrict__ Wl1,
                                             const float* __restrict__ bl1,
                                             const float* __restrict__ Wl2,
                                             const float* __restrict__ bl2,
                                             float* __restrict__ out) {
    __shared__ float grow[204];
    __shared__ float partial[2];
    int g = blockIdx.x;
    int t = threadIdx.x;
    for (int idx = t; idx < 200; idx += 128) grow[idx] = pooled[g * 200 + idx];
    if (t < 4) grow[200 + t] = xs[g * 4 + t];
    __syncthreads();
    float s = bl1[t];
    for (int k = 0; k < 204; ++k) s += grow[k] * Wl1[k * 128 + t];
    s = LEAKY(s);
    float v = s * Wl2[t];
    for (int off = 32; off > 0; off >>= 1) v += __shfl_down(v, off, 64);
    if ((t & 63) == 0) partial[t >> 6] = v;
    __syncthreads();
    if (t == 0) out[g] = partial[0] + partial[1] + bl2[0];
}

extern "C" void kernel_launch(void* const* d_in, const int* in_sizes, int n_in,
                              void* d_out, int out_size, void* d_ws, size_t ws_size,
                              hipStream_t stream) {
    const float* x    = (const float*)d_in[0];
    const int*   ei   = (const int*)d_in[1];
    const float* xs   = (const float*)d_in[2];
    const int*   batch= (const int*)d_in[3];
    const float* W0   = (const float*)d_in[4];
    const float* b0   = (const float*)d_in[5];
    const float* W1   = (const float*)d_in[6];
    const float* b1   = (const float*)d_in[7];
    const float* W2   = (const float*)d_in[8];
    const float* b2   = (const float*)d_in[9];
    const float* W3   = (const float*)d_in[10];
    const float* b3   = (const float*)d_in[11];
    const float* Wl1  = (const float*)d_in[12];
    const float* bl1  = (const float*)d_in[13];
    const float* Wl2  = (const float*)d_in[14];
    const float* bl2  = (const float*)d_in[15];
    float* out = (float*)d_out;

    const int N = in_sizes[0] / 4;   // 50000 nodes
    const int E = in_sizes[1] / 2;   // 400000 edges
    const int G = in_sizes[2] / 4;   // 500 graphs

    char* ws = (char*)d_ws;
    size_t off = 0;
    auto alloc = [&](size_t bytes) { void* p = ws + off; off += (bytes + 255) & ~size_t(255); return p; };
    float* buf0   = (float*)alloc((size_t)N * 200 * sizeof(float));
    float* buf1   = (float*)alloc((size_t)N * 200 * sizeof(float));
    float* dinv   = (float*)alloc((size_t)N * sizeof(float));
    float* px     = (float*)alloc((size_t)N * 4 * sizeof(float));
    float* pooled = (float*)alloc((size_t)G * 200 * sizeof(float));
    int*   cnt    = (int*)alloc((size_t)N * sizeof(int));
    int*   fillc  = (int*)alloc((size_t)N * sizeof(int));
    int*   rowptr = (int*)alloc(((size_t)N + 1) * sizeof(int));
    int*   col    = (int*)alloc((size_t)E * sizeof(int));
    float* wgt    = (float*)alloc((size_t)E * sizeof(float));

    const int B = 256;
    // CSR build (by destination) + norms
    k_zero2<<<(N + B - 1) / B, B, 0, stream>>>(cnt, fillc, N);
    k_count<<<(E + B - 1) / B, B, 0, stream>>>(ei, cnt, E);
    k_scan<<<1, 1024, 0, stream>>>(cnt, rowptr, N);
    k_dinv<<<(N + B - 1) / B, B, 0, stream>>>(cnt, dinv, N);
    k_fill<<<(E + B - 1) / B, B, 0, stream>>>(ei, dinv, rowptr, fillc, col, wgt, E);

    // layer 0: gather x (4-wide) then 4->200 GEMM
    k_gather4<<<(N + B - 1) / B, B, 0, stream>>>(x, dinv, rowptr, col, wgt, px, N);
    k_gemm_l0<<<(N * 50 + B - 1) / B, B, 0, stream>>>(px, W0, buf0, N);

    // layers 1..3: GEMM (bias+leaky fused) then gather-propagate
    const float* Wcur[3]  = {W1, W2, W3};
    const float* bprev[3] = {b0, b1, b2};
    for (int L = 0; L < 3; ++L) {
        k_gemm200<<<(N + 79) / 80, 256, 0, stream>>>(buf0, bprev[L], Wcur[L], buf1, N);
        k_gather200<<<(N * 50 + B - 1) / B, B, 0, stream>>>(buf1, dinv, rowptr, col, wgt, buf0, N);
    }

    // pool (applies leaky(p3 + b3)) + head MLP
    k_pool<<<G, 256, 0, stream>>>(buf0, b3, batch, N, pooled);
    k_mlp<<<G, 128, 0, stream>>>(pooled, xs, Wl1, bl1, Wl2, bl2, out);
}

// Round 5
// 548.967 us; speedup vs baseline: 7.7387x; 1.3093x over previous
//
#include <hip/hip_runtime.h>
#include <math.h>

#define LEAKY(v) ((v) > 0.0f ? (v) : 0.01f * (v))

typedef _Float16 v8h __attribute__((ext_vector_type(8)));
typedef float v4f __attribute__((ext_vector_type(4)));

// ================= CSR build =================
__global__ void k_zero2(int* __restrict__ cnt, int* __restrict__ fill, int n) {
    int i = blockIdx.x * blockDim.x + threadIdx.x;
    if (i < n) { cnt[i] = 0; fill[i] = 0; }
}

__global__ void k_count(const int* __restrict__ ei, int* __restrict__ cnt, int E) {
    int e = blockIdx.x * blockDim.x + threadIdx.x;
    if (e < E) atomicAdd(&cnt[ei[E + e]], 1);
}

__global__ __launch_bounds__(1024) void k_scan(const int* __restrict__ cnt,
                                               int* __restrict__ rowptr, int n) {
    __shared__ int ssum[1024];
    const int t = threadIdx.x;
    const int chunk = (n + 1023) / 1024;
    const int lo = t * chunk;
    const int hi = min(lo + chunk, n);
    int s = 0;
    for (int i = lo; i < hi; ++i) s += cnt[i];
    ssum[t] = s;
    __syncthreads();
    for (int off = 1; off < 1024; off <<= 1) {
        int v = (t >= off) ? ssum[t - off] : 0;
        __syncthreads();
        ssum[t] += v;
        __syncthreads();
    }
    int base = (t == 0) ? 0 : ssum[t - 1];
    for (int i = lo; i < hi; ++i) { rowptr[i] = base; base += cnt[i]; }
    if (hi == n) rowptr[n] = base;
}

__global__ void k_dinv(const int* __restrict__ cnt, float* __restrict__ dinv, int n) {
    int i = blockIdx.x * blockDim.x + threadIdx.x;
    if (i < n) dinv[i] = rsqrtf(1.0f + (float)cnt[i]);  // +1 self-loop
}

// adjacency entry: {src, weight} packed 8B
__global__ void k_fill(const int* __restrict__ ei, const float* __restrict__ dinv,
                       const int* __restrict__ rowptr, int* __restrict__ fill,
                       int2* __restrict__ adj, int E) {
    int e = blockIdx.x * blockDim.x + threadIdx.x;
    if (e < E) {
        int s = ei[e], d = ei[E + e];
        int pos = rowptr[d] + atomicAdd(&fill[d], 1);
        adj[pos] = make_int2(s, __float_as_int(dinv[s] * dinv[d]));
    }
}

// ================= W split: fp32 [200][200] -> transposed padded f16 hi/lo [208][224] =================
__global__ __launch_bounds__(256) void k_splitW(const float* __restrict__ W,
                                                _Float16* __restrict__ Wth,
                                                _Float16* __restrict__ Wtl) {
    int idx = blockIdx.x * blockDim.x + threadIdx.x;  // over 224*208
    if (idx >= 224 * 208) return;
    int k = idx / 208, n = idx - k * 208;
    float v = (k < 200 && n < 200) ? W[k * 200 + n] : 0.0f;
    _Float16 hi = (_Float16)v;
    _Float16 lo = (_Float16)(v - (float)hi);
    Wth[n * 224 + k] = hi;
    Wtl[n * 224 + k] = lo;
}

// ================= layer-0: gather x (4-wide), then 4->200 GEMM =================
__global__ void k_gather4(const float* __restrict__ x, const float* __restrict__ dinv,
                          const int* __restrict__ rowptr, const int2* __restrict__ adj,
                          float* __restrict__ px, int n) {
    int v = blockIdx.x * blockDim.x + threadIdx.x;
    if (v >= n) return;
    float w0 = dinv[v]; w0 *= w0;
    float4 xv = ((const float4*)x)[v];
    float4 acc = make_float4(xv.x * w0, xv.y * w0, xv.z * w0, xv.w * w0);
    int lo = rowptr[v], hi = rowptr[v + 1];
    for (int j = lo; j < hi; ++j) {
        int2 cw = adj[j];
        int s = cw.x; float w = __int_as_float(cw.y);
        float4 sv = ((const float4*)x)[s];
        acc.x += sv.x * w; acc.y += sv.y * w; acc.z += sv.z * w; acc.w += sv.w * w;
    }
    ((float4*)px)[v] = acc;
}

// p0 = px @ W0  (n x 4)@(4 x 200). Swizzled LDS for W0.
__global__ __launch_bounds__(256) void k_gemm_l0(const float* __restrict__ px,
                                                 const float* __restrict__ W0,
                                                 float* __restrict__ p0, int n) {
    __shared__ float Ws[4][224];
    for (int idx = threadIdx.x; idx < 800; idx += 256) {
        int k = idx / 200, c = idx - k * 200;
        Ws[k][c + ((c >> 5) << 2)] = W0[idx];
    }
    __syncthreads();
    int gid = blockIdx.x * blockDim.x + threadIdx.x;
    if (gid < n * 50) {
        int v = gid / 50, c4 = gid - v * 50;
        int c = c4 * 4, sc = c + ((c >> 5) << 2);
        float4 xv = ((const float4*)px)[v];
        float4 w0 = *(const float4*)&Ws[0][sc];
        float4 w1 = *(const float4*)&Ws[1][sc];
        float4 w2 = *(const float4*)&Ws[2][sc];
        float4 w3 = *(const float4*)&Ws[3][sc];
        float4 o;
        o.x = xv.x * w0.x + xv.y * w1.x + xv.z * w2.x + xv.w * w3.x;
        o.y = xv.x * w0.y + xv.y * w1.y + xv.z * w2.y + xv.w * w3.y;
        o.z = xv.x * w0.z + xv.y * w1.z + xv.z * w2.z + xv.w * w3.z;
        o.w = xv.x * w0.w + xv.y * w1.w + xv.z * w2.w + xv.w * w3.w;
        ((float4*)p0)[gid] = o;
    }
}

// ================= main GEMM via split-f16 MFMA =================
// T = leaky(P + bprev) @ W, fp32-accurate: Ah*Wh + Ah*Wl + Al*Wh.
// Block = 4 waves = 64 rows x 208 cols (200 valid). Wave = 16 rows.
// A: global->registers per wave (bias+leaky+split in VALU). W: LDS k-chunks of 32,
// from pre-transposed padded f16 Wt [n=208][k=224] so B-frags are contiguous-k b128 reads.
__global__ __launch_bounds__(256, 4) void k_gemm200_mfma(const float* __restrict__ P,
                                                         const float* __restrict__ bias,
                                                         const _Float16* __restrict__ Wth,
                                                         const _Float16* __restrict__ Wtl,
                                                         float* __restrict__ T, int M) {
    __shared__ _Float16 Wsh[208 * 32];
    __shared__ _Float16 Wsl[208 * 32];
    const int tid  = threadIdx.x;
    const int lane = tid & 63;
    const int wid  = tid >> 6;
    const int quad = lane >> 4;
    const int l16  = lane & 15;
    const int rowA = blockIdx.x * 64 + wid * 16 + l16;      // A-fragment row (m = lane&15)
    const int rowAc = min(rowA, M - 1);
    const float* Prow = P + (size_t)rowAc * 200;

    v4f acc[13];
#pragma unroll
    for (int t = 0; t < 13; ++t) acc[t] = 0.0f;

    for (int k0 = 0; k0 < 224; k0 += 32) {
        // ---- A fragments: 8 fp32 per lane from global, bias+leaky, split hi/lo ----
        v8h ah, al;
        int kb = k0 + quad * 8;
        if (kb < 200) {
            float4 pa = *(const float4*)(Prow + kb);
            float4 pb = *(const float4*)(Prow + kb + 4);
            float4 ba = *(const float4*)(bias + kb);
            float4 bb = *(const float4*)(bias + kb + 4);
            float av[8];
            av[0] = LEAKY(pa.x + ba.x); av[1] = LEAKY(pa.y + ba.y);
            av[2] = LEAKY(pa.z + ba.z); av[3] = LEAKY(pa.w + ba.w);
            av[4] = LEAKY(pb.x + bb.x); av[5] = LEAKY(pb.y + bb.y);
            av[6] = LEAKY(pb.z + bb.z); av[7] = LEAKY(pb.w + bb.w);
#pragma unroll
            for (int j = 0; j < 8; ++j) {
                _Float16 h = (_Float16)av[j];
                ah[j] = h;
                al[j] = (_Float16)(av[j] - (float)h);
            }
        } else {
#pragma unroll
            for (int j = 0; j < 8; ++j) { ah[j] = (_Float16)0.0f; al[j] = (_Float16)0.0f; }
        }
        // ---- stage W k-chunk into LDS (straight copy, pre-transposed source) ----
        __syncthreads();
        for (int idx = tid; idx < 832; idx += 256) {     // 208 rows x 4 x 16B
            int nr = idx >> 2, part = idx & 3;
            *(uint4*)&Wsh[nr * 32 + part * 8] = *(const uint4*)&Wth[nr * 224 + k0 + part * 8];
            *(uint4*)&Wsl[nr * 32 + part * 8] = *(const uint4*)&Wtl[nr * 224 + k0 + part * 8];
        }
        __syncthreads();
        // ---- 13 n-tiles x 3 MFMA ----
#pragma unroll
        for (int t = 0; t < 13; ++t) {
            int nidx = (t * 16 + l16) * 32 + quad * 8;
            v8h wh = *(const v8h*)&Wsh[nidx];
            v8h wl = *(const v8h*)&Wsl[nidx];
            acc[t] = __builtin_amdgcn_mfma_f32_16x16x32_f16(ah, wh, acc[t], 0, 0, 0);
            acc[t] = __builtin_amdgcn_mfma_f32_16x16x32_f16(ah, wl, acc[t], 0, 0, 0);
            acc[t] = __builtin_amdgcn_mfma_f32_16x16x32_f16(al, wh, acc[t], 0, 0, 0);
        }
    }
    // ---- epilogue: C/D layout col=lane&15, row=quad*4+reg ----
    const int rb = blockIdx.x * 64 + wid * 16 + quad * 4;
#pragma unroll
    for (int t = 0; t < 13; ++t) {
        int c = t * 16 + l16;
        if (c < 200) {
#pragma unroll
            for (int e = 0; e < 4; ++e) {
                int r = rb + e;
                if (r < M) T[(size_t)r * 200 + c] = acc[t][e];
            }
        }
    }
}

// ================= propagation (200-wide) via CSR gather =================
__global__ __launch_bounds__(256) void k_gather200(const float* __restrict__ t,
                                                   const float* __restrict__ dinv,
                                                   const int* __restrict__ rowptr,
                                                   const int2* __restrict__ adj,
                                                   float* __restrict__ p, int n) {
    int gid = blockIdx.x * blockDim.x + threadIdx.x;
    if (gid >= n * 50) return;
    int v = gid / 50, c4 = gid - v * 50;
    const float4* tp = (const float4*)t;
    float w0 = dinv[v]; w0 *= w0;
    float4 tv = tp[gid];
    float4 acc = make_float4(tv.x * w0, tv.y * w0, tv.z * w0, tv.w * w0);
    int lo = rowptr[v], hi = rowptr[v + 1];
#pragma unroll 4
    for (int j = lo; j < hi; ++j) {
        int2 cw = adj[j];                 // one 8B load; broadcast across node's lanes
        int s = cw.x; float w = __int_as_float(cw.y);
        float4 sv = tp[s * 50 + c4];      // coalesced 800B row read
        acc.x += sv.x * w; acc.y += sv.y * w; acc.z += sv.z * w; acc.w += sv.w * w;
    }
    ((float4*)p)[gid] = acc;
}

// ================= pooling: per-graph mean of leaky(p3 + b3) =================
__global__ __launch_bounds__(256) void k_pool(const float* __restrict__ p3,
                                              const float* __restrict__ b3,
                                              const int* __restrict__ batch, int n_nodes,
                                              float* __restrict__ pooled) {
    __shared__ int sb[2];
    int g = blockIdx.x;
    if (threadIdx.x == 0) {
        int lo = 0, hi = n_nodes;
        while (lo < hi) { int m = (lo + hi) >> 1; if (batch[m] < g) lo = m + 1; else hi = m; }
        sb[0] = lo;
        int lo2 = lo, hi2 = n_nodes;
        while (lo2 < hi2) { int m = (lo2 + hi2) >> 1; if (batch[m] < g + 1) lo2 = m + 1; else hi2 = m; }
        sb[1] = lo2;
    }
    __syncthreads();
    int lo = sb[0], hi = sb[1];
    int c = threadIdx.x;
    if (c < 200) {
        float bc = b3[c];
        float s = 0.0f;
        for (int nidx = lo; nidx < hi; ++nidx) {
            float v = p3[nidx * 200 + c] + bc;
            s += LEAKY(v);
        }
        float cnt = (float)(hi - lo);
        pooled[g * 200 + c] = s / fmaxf(cnt, 1.0f);
    }
}

// ================= head MLP =================
__global__ __launch_bounds__(128) void k_mlp(const float* __restrict__ pooled,
                                             const float* __restrict__ xs,
                                             const float* __restrict__ Wl1,
                                             const float* __restrict__ bl1,
                                             const float* __restrict__ Wl2,
                                             const float* __restrict__ bl2,
                                             float* __restrict__ out) {
    __shared__ float grow[204];
    __shared__ float partial[2];
    int g = blockIdx.x;
    int t = threadIdx.x;
    for (int idx = t; idx < 200; idx += 128) grow[idx] = pooled[g * 200 + idx];
    if (t < 4) grow[200 + t] = xs[g * 4 + t];
    __syncthreads();
    float s = bl1[t];
    for (int k = 0; k < 204; ++k) s += grow[k] * Wl1[k * 128 + t];
    s = LEAKY(s);
    float v = s * Wl2[t];
    for (int off = 32; off > 0; off >>= 1) v += __shfl_down(v, off, 64);
    if ((t & 63) == 0) partial[t >> 6] = v;
    __syncthreads();
    if (t == 0) out[g] = partial[0] + partial[1] + bl2[0];
}

extern "C" void kernel_launch(void* const* d_in, const int* in_sizes, int n_in,
                              void* d_out, int out_size, void* d_ws, size_t ws_size,
                              hipStream_t stream) {
    const float* x    = (const float*)d_in[0];
    const int*   ei   = (const int*)d_in[1];
    const float* xs   = (const float*)d_in[2];
    const int*   batch= (const int*)d_in[3];
    const float* W0   = (const float*)d_in[4];
    const float* b0   = (const float*)d_in[5];
    const float* W1   = (const float*)d_in[6];
    const float* b1   = (const float*)d_in[7];
    const float* W2   = (const float*)d_in[8];
    const float* b2   = (const float*)d_in[9];
    const float* W3   = (const float*)d_in[10];
    const float* b3   = (const float*)d_in[11];
    const float* Wl1  = (const float*)d_in[12];
    const float* bl1  = (const float*)d_in[13];
    const float* Wl2  = (const float*)d_in[14];
    const float* bl2  = (const float*)d_in[15];
    float* out = (float*)d_out;

    const int N = in_sizes[0] / 4;   // 50000 nodes
    const int E = in_sizes[1] / 2;   // 400000 edges
    const int G = in_sizes[2] / 4;   // 500 graphs

    char* ws = (char*)d_ws;
    size_t off = 0;
    auto alloc = [&](size_t bytes) { void* p = ws + off; off += (bytes + 255) & ~size_t(255); return p; };
    float* buf0   = (float*)alloc((size_t)N * 200 * sizeof(float));
    float* buf1   = (float*)alloc((size_t)N * 200 * sizeof(float));
    float* dinv   = (float*)alloc((size_t)N * sizeof(float));
    float* px     = (float*)alloc((size_t)N * 4 * sizeof(float));
    float* pooled = (float*)alloc((size_t)G * 200 * sizeof(float));
    int*   cnt    = (int*)alloc((size_t)N * sizeof(int));
    int*   fillc  = (int*)alloc((size_t)N * sizeof(int));
    int*   rowptr = (int*)alloc(((size_t)N + 1) * sizeof(int));
    int2*  adj    = (int2*)alloc((size_t)E * sizeof(int2));
    _Float16* Wth[3]; _Float16* Wtl[3];
    for (int i = 0; i < 3; ++i) {
        Wth[i] = (_Float16*)alloc(208 * 224 * sizeof(_Float16));
        Wtl[i] = (_Float16*)alloc(208 * 224 * sizeof(_Float16));
    }

    const int B = 256;
    // CSR build (by destination) + norms
    k_zero2<<<(N + B - 1) / B, B, 0, stream>>>(cnt, fillc, N);
    k_count<<<(E + B - 1) / B, B, 0, stream>>>(ei, cnt, E);
    k_scan<<<1, 1024, 0, stream>>>(cnt, rowptr, N);
    k_dinv<<<(N + B - 1) / B, B, 0, stream>>>(cnt, dinv, N);
    k_fill<<<(E + B - 1) / B, B, 0, stream>>>(ei, dinv, rowptr, fillc, adj, E);

    // W splits (hi/lo f16, transposed+padded) for layers 1..3
    const float* Wcur[3] = {W1, W2, W3};
    for (int i = 0; i < 3; ++i)
        k_splitW<<<(224 * 208 + B - 1) / B, B, 0, stream>>>(Wcur[i], Wth[i], Wtl[i]);

    // layer 0: gather x (4-wide) then 4->200 GEMM
    k_gather4<<<(N + B - 1) / B, B, 0, stream>>>(x, dinv, rowptr, adj, px, N);
    k_gemm_l0<<<(N * 50 + B - 1) / B, B, 0, stream>>>(px, W0, buf0, N);

    // layers 1..3: MFMA GEMM (bias+leaky fused) then gather-propagate
    const float* bprev[3] = {b0, b1, b2};
    for (int L = 0; L < 3; ++L) {
        k_gemm200_mfma<<<(N + 63) / 64, 256, 0, stream>>>(buf0, bprev[L], Wth[L], Wtl[L], buf1, N);
        k_gather200<<<(N * 50 + B - 1) / B, B, 0, stream>>>(buf1, dinv, rowptr, adj, buf0, N);
    }

    // pool (applies leaky(p3 + b3)) + head MLP
    k_pool<<<G, 256, 0, stream>>>(buf0, b3, batch, N, pooled);
    k_mlp<<<G, 128, 0, stream>>>(pooled, xs, Wl1, bl1, Wl2, bl2, out);
}

// Round 6
// 482.249 us; speedup vs baseline: 8.8094x; 1.1383x over previous
//
#include <hip/hip_runtime.h>
#include <math.h>

#define LEAKY(v) ((v) > 0.0f ? (v) : 0.01f * (v))

typedef _Float16 v8h __attribute__((ext_vector_type(8)));
typedef float v4f __attribute__((ext_vector_type(4)));

// ================= CSR build =================
__global__ void k_zero2(int* __restrict__ cnt, int* __restrict__ fill, int n) {
    int i = blockIdx.x * blockDim.x + threadIdx.x;
    if (i < n) { cnt[i] = 0; fill[i] = 0; }
}

__global__ void k_count(const int* __restrict__ ei, int* __restrict__ cnt, int E) {
    int e = blockIdx.x * blockDim.x + threadIdx.x;
    if (e < E) atomicAdd(&cnt[ei[E + e]], 1);
}

// ---- 3-phase multi-block exclusive scan (coalesced) ----
__global__ __launch_bounds__(256) void k_scan1(const int* __restrict__ cnt,
                                               int* __restrict__ rowptr,
                                               int* __restrict__ bsum, int n) {
    __shared__ int s[256];
    int t = threadIdx.x, i = blockIdx.x * 256 + t;
    int v = (i < n) ? cnt[i] : 0;
    s[t] = v;
    __syncthreads();
    for (int off = 1; off < 256; off <<= 1) {
        int u = (t >= off) ? s[t - off] : 0;
        __syncthreads();
        s[t] += u;
        __syncthreads();
    }
    if (i < n) rowptr[i] = s[t] - v;           // exclusive, no block base yet
    if (t == 255) bsum[blockIdx.x] = s[255];   // block total
}

__global__ __launch_bounds__(256) void k_scan2(int* __restrict__ bsum, int nb) {
    __shared__ int s[256];
    int t = threadIdx.x;
    int v = (t < nb) ? bsum[t] : 0;
    s[t] = v;
    __syncthreads();
    for (int off = 1; off < 256; off <<= 1) {
        int u = (t >= off) ? s[t - off] : 0;
        __syncthreads();
        s[t] += u;
        __syncthreads();
    }
    if (t < nb) bsum[t] = s[t] - v;            // exclusive block bases
}

__global__ __launch_bounds__(256) void k_scan3(int* __restrict__ rowptr,
                                               const int* __restrict__ bsum,
                                               int n, int E) {
    int i = blockIdx.x * 256 + threadIdx.x;
    if (i < n) rowptr[i] += bsum[blockIdx.x];
    if (i == 0) rowptr[n] = E;                 // total is exactly E
}

__global__ void k_dinv(const int* __restrict__ cnt, float* __restrict__ dinv, int n) {
    int i = blockIdx.x * blockDim.x + threadIdx.x;
    if (i < n) dinv[i] = rsqrtf(1.0f + (float)cnt[i]);  // +1 self-loop
}

// adjacency entry: {src, weight} packed 8B
__global__ void k_fill(const int* __restrict__ ei, const float* __restrict__ dinv,
                       const int* __restrict__ rowptr, int* __restrict__ fill,
                       int2* __restrict__ adj, int E) {
    int e = blockIdx.x * blockDim.x + threadIdx.x;
    if (e < E) {
        int s = ei[e], d = ei[E + e];
        int pos = rowptr[d] + atomicAdd(&fill[d], 1);
        adj[pos] = make_int2(s, __float_as_int(dinv[s] * dinv[d]));
    }
}

// ================= W split: fp32 [200][200] -> transposed padded f16 hi/lo [208][224] =================
__global__ __launch_bounds__(256) void k_splitW(const float* __restrict__ W,
                                                _Float16* __restrict__ Wth,
                                                _Float16* __restrict__ Wtl) {
    int idx = blockIdx.x * blockDim.x + threadIdx.x;  // over 224*208
    if (idx >= 224 * 208) return;
    int k = idx / 208, n = idx - k * 208;
    float v = (k < 200 && n < 200) ? W[k * 200 + n] : 0.0f;
    _Float16 hi = (_Float16)v;
    _Float16 lo = (_Float16)(v - (float)hi);
    Wth[n * 224 + k] = hi;
    Wtl[n * 224 + k] = lo;
}

// ================= layer-0: gather x (4-wide), then 4->200 GEMM =================
__global__ void k_gather4(const float* __restrict__ x, const float* __restrict__ dinv,
                          const int* __restrict__ rowptr, const int2* __restrict__ adj,
                          float* __restrict__ px, int n) {
    int v = blockIdx.x * blockDim.x + threadIdx.x;
    if (v >= n) return;
    float w0 = dinv[v]; w0 *= w0;
    float4 xv = ((const float4*)x)[v];
    float4 acc = make_float4(xv.x * w0, xv.y * w0, xv.z * w0, xv.w * w0);
    int lo = rowptr[v], hi = rowptr[v + 1];
    for (int j = lo; j < hi; ++j) {
        int2 cw = adj[j];
        int s = cw.x; float w = __int_as_float(cw.y);
        float4 sv = ((const float4*)x)[s];
        acc.x += sv.x * w; acc.y += sv.y * w; acc.z += sv.z * w; acc.w += sv.w * w;
    }
    ((float4*)px)[v] = acc;
}

// p0 = px @ W0  (n x 4)@(4 x 200). Swizzled LDS for W0.
__global__ __launch_bounds__(256) void k_gemm_l0(const float* __restrict__ px,
                                                 const float* __restrict__ W0,
                                                 float* __restrict__ p0, int n) {
    __shared__ float Ws[4][224];
    for (int idx = threadIdx.x; idx < 800; idx += 256) {
        int k = idx / 200, c = idx - k * 200;
        Ws[k][c + ((c >> 5) << 2)] = W0[idx];
    }
    __syncthreads();
    int gid = blockIdx.x * blockDim.x + threadIdx.x;
    if (gid < n * 50) {
        int v = gid / 50, c4 = gid - v * 50;
        int c = c4 * 4, sc = c + ((c >> 5) << 2);
        float4 xv = ((const float4*)px)[v];
        float4 w0 = *(const float4*)&Ws[0][sc];
        float4 w1 = *(const float4*)&Ws[1][sc];
        float4 w2 = *(const float4*)&Ws[2][sc];
        float4 w3 = *(const float4*)&Ws[3][sc];
        float4 o;
        o.x = xv.x * w0.x + xv.y * w1.x + xv.z * w2.x + xv.w * w3.x;
        o.y = xv.x * w0.y + xv.y * w1.y + xv.z * w2.y + xv.w * w3.y;
        o.z = xv.x * w0.z + xv.y * w1.z + xv.z * w2.z + xv.w * w3.z;
        o.w = xv.x * w0.w + xv.y * w1.w + xv.z * w2.w + xv.w * w3.w;
        ((float4*)p0)[gid] = o;
    }
}

// ================= main GEMM via split-f16 MFMA =================
// T = leaky(P + bprev) @ W, fp32-accurate: Ah*Wh + Ah*Wl + Al*Wh.
__global__ __launch_bounds__(256, 4) void k_gemm200_mfma(const float* __restrict__ P,
                                                         const float* __restrict__ bias,
                                                         const _Float16* __restrict__ Wth,
                                                         const _Float16* __restrict__ Wtl,
                                                         float* __restrict__ T, int M) {
    __shared__ _Float16 Wsh[208 * 32];
    __shared__ _Float16 Wsl[208 * 32];
    const int tid  = threadIdx.x;
    const int lane = tid & 63;
    const int wid  = tid >> 6;
    const int quad = lane >> 4;
    const int l16  = lane & 15;
    const int rowA = blockIdx.x * 64 + wid * 16 + l16;
    const int rowAc = min(rowA, M - 1);
    const float* Prow = P + (size_t)rowAc * 200;

    v4f acc[13];
#pragma unroll
    for (int t = 0; t < 13; ++t) acc[t] = 0.0f;

    for (int k0 = 0; k0 < 224; k0 += 32) {
        v8h ah, al;
        int kb = k0 + quad * 8;
        if (kb < 200) {
            float4 pa = *(const float4*)(Prow + kb);
            float4 pb = *(const float4*)(Prow + kb + 4);
            float4 ba = *(const float4*)(bias + kb);
            float4 bb = *(const float4*)(bias + kb + 4);
            float av[8];
            av[0] = LEAKY(pa.x + ba.x); av[1] = LEAKY(pa.y + ba.y);
            av[2] = LEAKY(pa.z + ba.z); av[3] = LEAKY(pa.w + ba.w);
            av[4] = LEAKY(pb.x + bb.x); av[5] = LEAKY(pb.y + bb.y);
            av[6] = LEAKY(pb.z + bb.z); av[7] = LEAKY(pb.w + bb.w);
#pragma unroll
            for (int j = 0; j < 8; ++j) {
                _Float16 h = (_Float16)av[j];
                ah[j] = h;
                al[j] = (_Float16)(av[j] - (float)h);
            }
        } else {
#pragma unroll
            for (int j = 0; j < 8; ++j) { ah[j] = (_Float16)0.0f; al[j] = (_Float16)0.0f; }
        }
        __syncthreads();
        for (int idx = tid; idx < 832; idx += 256) {     // 208 rows x 4 x 16B
            int nr = idx >> 2, part = idx & 3;
            *(uint4*)&Wsh[nr * 32 + part * 8] = *(const uint4*)&Wth[nr * 224 + k0 + part * 8];
            *(uint4*)&Wsl[nr * 32 + part * 8] = *(const uint4*)&Wtl[nr * 224 + k0 + part * 8];
        }
        __syncthreads();
#pragma unroll
        for (int t = 0; t < 13; ++t) {
            int nidx = (t * 16 + l16) * 32 + quad * 8;
            v8h wh = *(const v8h*)&Wsh[nidx];
            v8h wl = *(const v8h*)&Wsl[nidx];
            acc[t] = __builtin_amdgcn_mfma_f32_16x16x32_f16(ah, wh, acc[t], 0, 0, 0);
            acc[t] = __builtin_amdgcn_mfma_f32_16x16x32_f16(ah, wl, acc[t], 0, 0, 0);
            acc[t] = __builtin_amdgcn_mfma_f32_16x16x32_f16(al, wh, acc[t], 0, 0, 0);
        }
    }
    const int rb = blockIdx.x * 64 + wid * 16 + quad * 4;
#pragma unroll
    for (int t = 0; t < 13; ++t) {
        int c = t * 16 + l16;
        if (c < 200) {
#pragma unroll
            for (int e = 0; e < 4; ++e) {
                int r = rb + e;
                if (r < M) T[(size_t)r * 200 + c] = acc[t][e];
            }
        }
    }
}

// ================= propagation (200-wide) via CSR gather =================
// thread = (node, float4 chunk); dual accumulators for ILP.
__global__ __launch_bounds__(256) void k_gather200(const float* __restrict__ t,
                                                   const float* __restrict__ dinv,
                                                   const int* __restrict__ rowptr,
                                                   const int2* __restrict__ adj,
                                                   float* __restrict__ p, int n) {
    int gid = blockIdx.x * blockDim.x + threadIdx.x;
    if (gid >= n * 50) return;
    int v = gid / 50, c4 = gid - v * 50;
    const float4* tp = (const float4*)t;
    float w0 = dinv[v]; w0 *= w0;
    float4 tv = tp[gid];
    float4 a0 = make_float4(tv.x * w0, tv.y * w0, tv.z * w0, tv.w * w0);
    float4 a1 = make_float4(0.f, 0.f, 0.f, 0.f);
    int lo = rowptr[v], hi = rowptr[v + 1];
    int j = lo;
#pragma unroll 2
    for (; j + 1 < hi; j += 2) {
        int2 cw0 = adj[j], cw1 = adj[j + 1];
        float wa = __int_as_float(cw0.y), wb = __int_as_float(cw1.y);
        float4 s0 = tp[cw0.x * 50 + c4];
        float4 s1 = tp[cw1.x * 50 + c4];
        a0.x += s0.x * wa; a0.y += s0.y * wa; a0.z += s0.z * wa; a0.w += s0.w * wa;
        a1.x += s1.x * wb; a1.y += s1.y * wb; a1.z += s1.z * wb; a1.w += s1.w * wb;
    }
    if (j < hi) {
        int2 cw = adj[j];
        float w = __int_as_float(cw.y);
        float4 sv = tp[cw.x * 50 + c4];
        a0.x += sv.x * w; a0.y += sv.y * w; a0.z += sv.z * w; a0.w += sv.w * w;
    }
    a0.x += a1.x; a0.y += a1.y; a0.z += a1.z; a0.w += a1.w;
    ((float4*)p)[gid] = a0;
}

// ================= pooling: per-graph mean of leaky(p3 + b3) =================
__global__ __launch_bounds__(256) void k_pool(const float* __restrict__ p3,
                                              const float* __restrict__ b3,
                                              const int* __restrict__ batch, int n_nodes,
                                              float* __restrict__ pooled) {
    __shared__ int sb[2];
    int g = blockIdx.x;
    if (threadIdx.x == 0) {
        int lo = 0, hi = n_nodes;
        while (lo < hi) { int m = (lo + hi) >> 1; if (batch[m] < g) lo = m + 1; else hi = m; }
        sb[0] = lo;
        int lo2 = lo, hi2 = n_nodes;
        while (lo2 < hi2) { int m = (lo2 + hi2) >> 1; if (batch[m] < g + 1) lo2 = m + 1; else hi2 = m; }
        sb[1] = lo2;
    }
    __syncthreads();
    int lo = sb[0], hi = sb[1];
    int c = threadIdx.x;
    if (c < 200) {
        float bc = b3[c];
        float s = 0.0f;
        for (int nidx = lo; nidx < hi; ++nidx) {
            float v = p3[nidx * 200 + c] + bc;
            s += LEAKY(v);
        }
        float cnt = (float)(hi - lo);
        pooled[g * 200 + c] = s / fmaxf(cnt, 1.0f);
    }
}

// ================= head MLP =================
__global__ __launch_bounds__(128) void k_mlp(const float* __restrict__ pooled,
                                             const float* __restrict__ xs,
                                             const float* __restrict__ Wl1,
                                             const float* __restrict__ bl1,
                                             const float* __restrict__ Wl2,
                                             const float* __restrict__ bl2,
                                             float* __restrict__ out) {
    __shared__ float grow[204];
    __shared__ float partial[2];
    int g = blockIdx.x;
    int t = threadIdx.x;
    for (int idx = t; idx < 200; idx += 128) grow[idx] = pooled[g * 200 + idx];
    if (t < 4) grow[200 + t] = xs[g * 4 + t];
    __syncthreads();
    float s = bl1[t];
    for (int k = 0; k < 204; ++k) s += grow[k] * Wl1[k * 128 + t];
    s = LEAKY(s);
    float v = s * Wl2[t];
    for (int off = 32; off > 0; off >>= 1) v += __shfl_down(v, off, 64);
    if ((t & 63) == 0) partial[t >> 6] = v;
    __syncthreads();
    if (t == 0) out[g] = partial[0] + partial[1] + bl2[0];
}

extern "C" void kernel_launch(void* const* d_in, const int* in_sizes, int n_in,
                              void* d_out, int out_size, void* d_ws, size_t ws_size,
                              hipStream_t stream) {
    const float* x    = (const float*)d_in[0];
    const int*   ei   = (const int*)d_in[1];
    const float* xs   = (const float*)d_in[2];
    const int*   batch= (const int*)d_in[3];
    const float* W0   = (const float*)d_in[4];
    const float* b0   = (const float*)d_in[5];
    const float* W1   = (const float*)d_in[6];
    const float* b1   = (const float*)d_in[7];
    const float* W2   = (const float*)d_in[8];
    const float* b2   = (const float*)d_in[9];
    const float* W3   = (const float*)d_in[10];
    const float* b3   = (const float*)d_in[11];
    const float* Wl1  = (const float*)d_in[12];
    const float* bl1  = (const float*)d_in[13];
    const float* Wl2  = (const float*)d_in[14];
    const float* bl2  = (const float*)d_in[15];
    float* out = (float*)d_out;

    const int N = in_sizes[0] / 4;   // 50000 nodes
    const int E = in_sizes[1] / 2;   // 400000 edges
    const int G = in_sizes[2] / 4;   // 500 graphs

    char* ws = (char*)d_ws;
    size_t off = 0;
    auto alloc = [&](size_t bytes) { void* p = ws + off; off += (bytes + 255) & ~size_t(255); return p; };
    float* buf0   = (float*)alloc((size_t)N * 200 * sizeof(float));
    float* buf1   = (float*)alloc((size_t)N * 200 * sizeof(float));
    float* dinv   = (float*)alloc((size_t)N * sizeof(float));
    float* px     = (float*)alloc((size_t)N * 4 * sizeof(float));
    float* pooled = (float*)alloc((size_t)G * 200 * sizeof(float));
    int*   cnt    = (int*)alloc((size_t)N * sizeof(int));
    int*   fillc  = (int*)alloc((size_t)N * sizeof(int));
    int*   rowptr = (int*)alloc(((size_t)N + 1) * sizeof(int));
    int*   bsum   = (int*)alloc(256 * sizeof(int));
    int2*  adj    = (int2*)alloc((size_t)E * sizeof(int2));
    _Float16* Wth[3]; _Float16* Wtl[3];
    for (int i = 0; i < 3; ++i) {
        Wth[i] = (_Float16*)alloc(208 * 224 * sizeof(_Float16));
        Wtl[i] = (_Float16*)alloc(208 * 224 * sizeof(_Float16));
    }

    const int B = 256;
    const int nblk = (N + 255) / 256;   // 196 <= 256
    // CSR build (by destination) + norms
    k_zero2<<<(N + B - 1) / B, B, 0, stream>>>(cnt, fillc, N);
    k_count<<<(E + B - 1) / B, B, 0, stream>>>(ei, cnt, E);
    k_scan1<<<nblk, 256, 0, stream>>>(cnt, rowptr, bsum, N);
    k_scan2<<<1, 256, 0, stream>>>(bsum, nblk);
    k_scan3<<<nblk, 256, 0, stream>>>(rowptr, bsum, N, E);
    k_dinv<<<(N + B - 1) / B, B, 0, stream>>>(cnt, dinv, N);
    k_fill<<<(E + B - 1) / B, B, 0, stream>>>(ei, dinv, rowptr, fillc, adj, E);

    // W splits (hi/lo f16, transposed+padded) for layers 1..3
    const float* Wcur[3] = {W1, W2, W3};
    for (int i = 0; i < 3; ++i)
        k_splitW<<<(224 * 208 + B - 1) / B, B, 0, stream>>>(Wcur[i], Wth[i], Wtl[i]);

    // layer 0: gather x (4-wide) then 4->200 GEMM
    k_gather4<<<(N + B - 1) / B, B, 0, stream>>>(x, dinv, rowptr, adj, px, N);
    k_gemm_l0<<<(N * 50 + B - 1) / B, B, 0, stream>>>(px, W0, buf0, N);

    // layers 1..3: MFMA GEMM (bias+leaky fused) then gather-propagate
    const float* bprev[3] = {b0, b1, b2};
    for (int L = 0; L < 3; ++L) {
        k_gemm200_mfma<<<(N + 63) / 64, 256, 0, stream>>>(buf0, bprev[L], Wth[L], Wtl[L], buf1, N);
        k_gather200<<<(N * 50 + B - 1) / B, B, 0, stream>>>(buf1, dinv, rowptr, adj, buf0, N);
    }

    // pool (applies leaky(p3 + b3)) + head MLP
    k_pool<<<G, 256, 0, stream>>>(buf0, b3, batch, N, pooled);
    k_mlp<<<G, 128, 0, stream>>>(pooled, xs, Wl1, bl1, Wl2, bl2, out);
}

// Round 7
// 456.753 us; speedup vs baseline: 9.3011x; 1.0558x over previous
//
#include <hip/hip_runtime.h>
#include <math.h>

#define LEAKY(v) ((v) > 0.0f ? (v) : 0.01f * (v))

typedef _Float16 v8h __attribute__((ext_vector_type(8)));
typedef float v4f __attribute__((ext_vector_type(4)));

// ================= CSR build =================
__global__ void k_zero(int* __restrict__ cnt, int n) {
    int i = blockIdx.x * blockDim.x + threadIdx.x;
    if (i < n) cnt[i] = 0;
}

__global__ void k_count(const int* __restrict__ ei, int* __restrict__ cnt, int E) {
    int e = blockIdx.x * blockDim.x + threadIdx.x;
    if (e < E) atomicAdd(&cnt[ei[E + e]], 1);
}

// ---- 3-phase multi-block exclusive scan (coalesced) ----
__global__ __launch_bounds__(256) void k_scan1(const int* __restrict__ cnt,
                                               int* __restrict__ rowptr,
                                               int* __restrict__ bsum, int n) {
    __shared__ int s[256];
    int t = threadIdx.x, i = blockIdx.x * 256 + t;
    int v = (i < n) ? cnt[i] : 0;
    s[t] = v;
    __syncthreads();
    for (int off = 1; off < 256; off <<= 1) {
        int u = (t >= off) ? s[t - off] : 0;
        __syncthreads();
        s[t] += u;
        __syncthreads();
    }
    if (i < n) rowptr[i] = s[t] - v;
    if (t == 255) bsum[blockIdx.x] = s[255];
}

__global__ __launch_bounds__(256) void k_scan2(int* __restrict__ bsum, int nb) {
    __shared__ int s[256];
    int t = threadIdx.x;
    int v = (t < nb) ? bsum[t] : 0;
    s[t] = v;
    __syncthreads();
    for (int off = 1; off < 256; off <<= 1) {
        int u = (t >= off) ? s[t - off] : 0;
        __syncthreads();
        s[t] += u;
        __syncthreads();
    }
    if (t < nb) bsum[t] = s[t] - v;
}

// adds block base AND computes dinv (fused elementwise pass)
__global__ __launch_bounds__(256) void k_scan3(int* __restrict__ rowptr,
                                               const int* __restrict__ bsum,
                                               const int* __restrict__ cnt,
                                               float* __restrict__ dinv, int n) {
    int i = blockIdx.x * 256 + threadIdx.x;
    if (i < n) {
        rowptr[i] += bsum[blockIdx.x];
        dinv[i] = rsqrtf(1.0f + (float)cnt[i]);  // +1 self-loop
    }
}

// atomicAdd directly on rowptr: after this, rowptr[d] = end(d); start(d) = rowptr[d-1].
__global__ void k_fill(const int* __restrict__ ei, const float* __restrict__ dinv,
                       int* __restrict__ rowptr, int2* __restrict__ adj, int E) {
    int e = blockIdx.x * blockDim.x + threadIdx.x;
    if (e < E) {
        int s = ei[e], d = ei[E + e];
        int pos = atomicAdd(&rowptr[d], 1);
        adj[pos] = make_int2(s, __float_as_int(dinv[s] * dinv[d]));
    }
}

// ================= W split (3 layers in one launch): fp32 [200][200] -> f16 hi/lo [208][224] T =================
__global__ __launch_bounds__(256) void k_splitW3(const float* __restrict__ W1,
                                                 const float* __restrict__ W2,
                                                 const float* __restrict__ W3,
                                                 _Float16* __restrict__ th0, _Float16* __restrict__ tl0,
                                                 _Float16* __restrict__ th1, _Float16* __restrict__ tl1,
                                                 _Float16* __restrict__ th2, _Float16* __restrict__ tl2) {
    int layer = blockIdx.y;
    const float* W = (layer == 0) ? W1 : (layer == 1) ? W2 : W3;
    _Float16* Wth = (layer == 0) ? th0 : (layer == 1) ? th1 : th2;
    _Float16* Wtl = (layer == 0) ? tl0 : (layer == 1) ? tl1 : tl2;
    int idx = blockIdx.x * blockDim.x + threadIdx.x;
    if (idx >= 224 * 208) return;
    int k = idx / 208, n = idx - k * 208;
    float v = (k < 200 && n < 200) ? W[k * 200 + n] : 0.0f;
    _Float16 hi = (_Float16)v;
    _Float16 lo = (_Float16)(v - (float)hi);
    Wth[n * 224 + k] = hi;
    Wtl[n * 224 + k] = lo;
}

// ================= layer-0 propagation: gather x (4-wide) =================
__global__ void k_gather4(const float* __restrict__ x, const float* __restrict__ dinv,
                          const int* __restrict__ rowptr, const int2* __restrict__ adj,
                          float* __restrict__ px, int n) {
    int v = blockIdx.x * blockDim.x + threadIdx.x;
    if (v >= n) return;
    float w0 = dinv[v]; w0 *= w0;
    float4 xv = ((const float4*)x)[v];
    float4 acc = make_float4(xv.x * w0, xv.y * w0, xv.z * w0, xv.w * w0);
    int lo = v ? rowptr[v - 1] : 0;
    int hi = rowptr[v];
    for (int j = lo; j < hi; ++j) {
        int2 cw = adj[j];
        int s = cw.x; float w = __int_as_float(cw.y);
        float4 sv = ((const float4*)x)[s];
        acc.x += sv.x * w; acc.y += sv.y * w; acc.z += sv.z * w; acc.w += sv.w * w;
    }
    ((float4*)px)[v] = acc;
}

// ================= layer-1 GEMM: T = leaky(px@W0 + b0) @ W1, A synthesized from px =================
__global__ __launch_bounds__(256, 4) void k_gemm200_mfma_l0(const float* __restrict__ px,
                                                            const float* __restrict__ W0,
                                                            const float* __restrict__ b0,
                                                            const _Float16* __restrict__ Wth,
                                                            const _Float16* __restrict__ Wtl,
                                                            float* __restrict__ T, int M) {
    __shared__ _Float16 Wsh[208 * 32];
    __shared__ _Float16 Wsl[208 * 32];
    __shared__ float W0s[4][200];
    __shared__ float b0s[200];
    const int tid  = threadIdx.x;
    const int lane = tid & 63;
    const int wid  = tid >> 6;
    const int quad = lane >> 4;
    const int l16  = lane & 15;
    const int rowA = blockIdx.x * 64 + wid * 16 + l16;
    const int rowAc = min(rowA, M - 1);
    const float4 pxv = ((const float4*)px)[rowAc];

    for (int idx = tid; idx < 1000; idx += 256) {
        if (idx < 800) W0s[idx / 200][idx % 200] = W0[idx];
        else b0s[idx - 800] = b0[idx - 800];
    }
    __syncthreads();

    v4f acc[13];
#pragma unroll
    for (int t = 0; t < 13; ++t) acc[t] = 0.0f;

    for (int k0 = 0; k0 < 224; k0 += 32) {
        v8h ah, al;
        int kb = k0 + quad * 8;
        if (kb < 200) {
#pragma unroll
            for (int j = 0; j < 8; ++j) {
                int k = kb + j;
                float pv = pxv.x * W0s[0][k] + pxv.y * W0s[1][k]
                         + pxv.z * W0s[2][k] + pxv.w * W0s[3][k] + b0s[k];
                pv = LEAKY(pv);
                _Float16 h = (_Float16)pv;
                ah[j] = h;
                al[j] = (_Float16)(pv - (float)h);
            }
        } else {
#pragma unroll
            for (int j = 0; j < 8; ++j) { ah[j] = (_Float16)0.0f; al[j] = (_Float16)0.0f; }
        }
        __syncthreads();
        for (int idx = tid; idx < 832; idx += 256) {
            int nr = idx >> 2, part = idx & 3;
            *(uint4*)&Wsh[nr * 32 + part * 8] = *(const uint4*)&Wth[nr * 224 + k0 + part * 8];
            *(uint4*)&Wsl[nr * 32 + part * 8] = *(const uint4*)&Wtl[nr * 224 + k0 + part * 8];
        }
        __syncthreads();
#pragma unroll
        for (int t = 0; t < 13; ++t) {
            int nidx = (t * 16 + l16) * 32 + quad * 8;
            v8h wh = *(const v8h*)&Wsh[nidx];
            v8h wl = *(const v8h*)&Wsl[nidx];
            acc[t] = __builtin_amdgcn_mfma_f32_16x16x32_f16(ah, wh, acc[t], 0, 0, 0);
            acc[t] = __builtin_amdgcn_mfma_f32_16x16x32_f16(ah, wl, acc[t], 0, 0, 0);
            acc[t] = __builtin_amdgcn_mfma_f32_16x16x32_f16(al, wh, acc[t], 0, 0, 0);
        }
    }
    const int rb = blockIdx.x * 64 + wid * 16 + quad * 4;
#pragma unroll
    for (int t = 0; t < 13; ++t) {
        int c = t * 16 + l16;
        if (c < 200) {
#pragma unroll
            for (int e = 0; e < 4; ++e) {
                int r = rb + e;
                if (r < M) T[(size_t)r * 200 + c] = acc[t][e];
            }
        }
    }
}

// ================= layers 2-3 GEMM: T = leaky(P + bprev) @ W, split-f16 MFMA =================
__global__ __launch_bounds__(256, 4) void k_gemm200_mfma(const float* __restrict__ P,
                                                         const float* __restrict__ bias,
                                                         const _Float16* __restrict__ Wth,
                                                         const _Float16* __restrict__ Wtl,
                                                         float* __restrict__ T, int M) {
    __shared__ _Float16 Wsh[208 * 32];
    __shared__ _Float16 Wsl[208 * 32];
    const int tid  = threadIdx.x;
    const int lane = tid & 63;
    const int wid  = tid >> 6;
    const int quad = lane >> 4;
    const int l16  = lane & 15;
    const int rowA = blockIdx.x * 64 + wid * 16 + l16;
    const int rowAc = min(rowA, M - 1);
    const float* Prow = P + (size_t)rowAc * 200;

    v4f acc[13];
#pragma unroll
    for (int t = 0; t < 13; ++t) acc[t] = 0.0f;

    for (int k0 = 0; k0 < 224; k0 += 32) {
        v8h ah, al;
        int kb = k0 + quad * 8;
        if (kb < 200) {
            float4 pa = *(const float4*)(Prow + kb);
            float4 pb = *(const float4*)(Prow + kb + 4);
            float4 ba = *(const float4*)(bias + kb);
            float4 bb = *(const float4*)(bias + kb + 4);
            float av[8];
            av[0] = LEAKY(pa.x + ba.x); av[1] = LEAKY(pa.y + ba.y);
            av[2] = LEAKY(pa.z + ba.z); av[3] = LEAKY(pa.w + ba.w);
            av[4] = LEAKY(pb.x + bb.x); av[5] = LEAKY(pb.y + bb.y);
            av[6] = LEAKY(pb.z + bb.z); av[7] = LEAKY(pb.w + bb.w);
#pragma unroll
            for (int j = 0; j < 8; ++j) {
                _Float16 h = (_Float16)av[j];
                ah[j] = h;
                al[j] = (_Float16)(av[j] - (float)h);
            }
        } else {
#pragma unroll
            for (int j = 0; j < 8; ++j) { ah[j] = (_Float16)0.0f; al[j] = (_Float16)0.0f; }
        }
        __syncthreads();
        for (int idx = tid; idx < 832; idx += 256) {
            int nr = idx >> 2, part = idx & 3;
            *(uint4*)&Wsh[nr * 32 + part * 8] = *(const uint4*)&Wth[nr * 224 + k0 + part * 8];
            *(uint4*)&Wsl[nr * 32 + part * 8] = *(const uint4*)&Wtl[nr * 224 + k0 + part * 8];
        }
        __syncthreads();
#pragma unroll
        for (int t = 0; t < 13; ++t) {
            int nidx = (t * 16 + l16) * 32 + quad * 8;
            v8h wh = *(const v8h*)&Wsh[nidx];
            v8h wl = *(const v8h*)&Wsl[nidx];
            acc[t] = __builtin_amdgcn_mfma_f32_16x16x32_f16(ah, wh, acc[t], 0, 0, 0);
            acc[t] = __builtin_amdgcn_mfma_f32_16x16x32_f16(ah, wl, acc[t], 0, 0, 0);
            acc[t] = __builtin_amdgcn_mfma_f32_16x16x32_f16(al, wh, acc[t], 0, 0, 0);
        }
    }
    const int rb = blockIdx.x * 64 + wid * 16 + quad * 4;
#pragma unroll
    for (int t = 0; t < 13; ++t) {
        int c = t * 16 + l16;
        if (c < 200) {
#pragma unroll
            for (int e = 0; e < 4; ++e) {
                int r = rb + e;
                if (r < M) T[(size_t)r * 200 + c] = acc[t][e];
            }
        }
    }
}

// ================= propagation (200-wide) via CSR gather, 4-way ILP =================
__global__ __launch_bounds__(256) void k_gather200(const float* __restrict__ t,
                                                   const float* __restrict__ dinv,
                                                   const int* __restrict__ rowptr,
                                                   const int2* __restrict__ adj,
                                                   float* __restrict__ p, int n) {
    int gid = blockIdx.x * blockDim.x + threadIdx.x;
    if (gid >= n * 50) return;
    int v = gid / 50, c4 = gid - v * 50;
    const float4* tp = (const float4*)t;
    float w0 = dinv[v]; w0 *= w0;
    float4 tv = tp[gid];
    float4 a0 = make_float4(tv.x * w0, tv.y * w0, tv.z * w0, tv.w * w0);
    float4 a1 = make_float4(0.f, 0.f, 0.f, 0.f);
    float4 a2 = make_float4(0.f, 0.f, 0.f, 0.f);
    float4 a3 = make_float4(0.f, 0.f, 0.f, 0.f);
    int lo = v ? rowptr[v - 1] : 0;
    int hi = rowptr[v];
    int j = lo;
    for (; j + 3 < hi; j += 4) {
        int2 e0 = adj[j], e1 = adj[j + 1], e2 = adj[j + 2], e3 = adj[j + 3];
        float w0e = __int_as_float(e0.y), w1e = __int_as_float(e1.y);
        float w2e = __int_as_float(e2.y), w3e = __int_as_float(e3.y);
        float4 s0 = tp[e0.x * 50 + c4];
        float4 s1 = tp[e1.x * 50 + c4];
        float4 s2 = tp[e2.x * 50 + c4];
        float4 s3 = tp[e3.x * 50 + c4];
        a0.x += s0.x * w0e; a0.y += s0.y * w0e; a0.z += s0.z * w0e; a0.w += s0.w * w0e;
        a1.x += s1.x * w1e; a1.y += s1.y * w1e; a1.z += s1.z * w1e; a1.w += s1.w * w1e;
        a2.x += s2.x * w2e; a2.y += s2.y * w2e; a2.z += s2.z * w2e; a2.w += s2.w * w2e;
        a3.x += s3.x * w3e; a3.y += s3.y * w3e; a3.z += s3.z * w3e; a3.w += s3.w * w3e;
    }
    for (; j < hi; ++j) {
        int2 cw = adj[j];
        float w = __int_as_float(cw.y);
        float4 sv = tp[cw.x * 50 + c4];
        a0.x += sv.x * w; a0.y += sv.y * w; a0.z += sv.z * w; a0.w += sv.w * w;
    }
    a0.x += a1.x + a2.x + a3.x;
    a0.y += a1.y + a2.y + a3.y;
    a0.z += a1.z + a2.z + a3.z;
    a0.w += a1.w + a2.w + a3.w;
    ((float4*)p)[gid] = a0;
}

// ================= fused pool + head MLP =================
__global__ __launch_bounds__(256) void k_poolmlp(const float* __restrict__ p3,
                                                 const float* __restrict__ b3,
                                                 const int* __restrict__ batch, int n_nodes,
                                                 const float* __restrict__ xs,
                                                 const float* __restrict__ Wl1,
                                                 const float* __restrict__ bl1,
                                                 const float* __restrict__ Wl2,
                                                 const float* __restrict__ bl2,
                                                 float* __restrict__ out) {
    __shared__ float grow[204];
    __shared__ float partial[2];
    __shared__ int sb[2];
    int g = blockIdx.x;
    int t = threadIdx.x;
    if (t == 0) {
        int lo = 0, hi = n_nodes;
        while (lo < hi) { int m = (lo + hi) >> 1; if (batch[m] < g) lo = m + 1; else hi = m; }
        sb[0] = lo;
        int lo2 = lo, hi2 = n_nodes;
        while (lo2 < hi2) { int m = (lo2 + hi2) >> 1; if (batch[m] < g + 1) lo2 = m + 1; else hi2 = m; }
        sb[1] = lo2;
    }
    __syncthreads();
    int lo = sb[0], hi = sb[1];
    if (t < 200) {
        float bc = b3[t];
        float s = 0.0f;
        for (int i = lo; i < hi; ++i) {
            float v = p3[(size_t)i * 200 + t] + bc;
            s += LEAKY(v);
        }
        grow[t] = s / fmaxf((float)(hi - lo), 1.0f);
    }
    if (t < 4) grow[200 + t] = xs[g * 4 + t];
    __syncthreads();
    float hv = 0.0f;
    if (t < 128) {
        float s = bl1[t];
        for (int k = 0; k < 204; ++k) s += grow[k] * Wl1[k * 128 + t];
        s = LEAKY(s);
        hv = s * Wl2[t];
    }
    for (int off = 32; off > 0; off >>= 1) hv += __shfl_down(hv, off, 64);
    if (t < 128 && (t & 63) == 0) partial[t >> 6] = hv;
    __syncthreads();
    if (t == 0) out[g] = partial[0] + partial[1] + bl2[0];
}

extern "C" void kernel_launch(void* const* d_in, const int* in_sizes, int n_in,
                              void* d_out, int out_size, void* d_ws, size_t ws_size,
                              hipStream_t stream) {
    const float* x    = (const float*)d_in[0];
    const int*   ei   = (const int*)d_in[1];
    const float* xs   = (const float*)d_in[2];
    const int*   batch= (const int*)d_in[3];
    const float* W0   = (const float*)d_in[4];
    const float* b0   = (const float*)d_in[5];
    const float* W1   = (const float*)d_in[6];
    const float* b1   = (const float*)d_in[7];
    const float* W2   = (const float*)d_in[8];
    const float* b2   = (const float*)d_in[9];
    const float* W3   = (const float*)d_in[10];
    const float* b3   = (const float*)d_in[11];
    const float* Wl1  = (const float*)d_in[12];
    const float* bl1  = (const float*)d_in[13];
    const float* Wl2  = (const float*)d_in[14];
    const float* bl2  = (const float*)d_in[15];
    float* out = (float*)d_out;

    const int N = in_sizes[0] / 4;   // 50000 nodes
    const int E = in_sizes[1] / 2;   // 400000 edges
    const int G = in_sizes[2] / 4;   // 500 graphs

    char* ws = (char*)d_ws;
    size_t off = 0;
    auto alloc = [&](size_t bytes) { void* p = ws + off; off += (bytes + 255) & ~size_t(255); return p; };
    float* buf0   = (float*)alloc((size_t)N * 200 * sizeof(float));
    float* buf1   = (float*)alloc((size_t)N * 200 * sizeof(float));
    float* dinv   = (float*)alloc((size_t)N * sizeof(float));
    float* px     = (float*)alloc((size_t)N * 4 * sizeof(float));
    int*   cnt    = (int*)alloc((size_t)N * sizeof(int));
    int*   rowptr = (int*)alloc(((size_t)N + 1) * sizeof(int));
    int*   bsum   = (int*)alloc(256 * sizeof(int));
    int2*  adj    = (int2*)alloc((size_t)E * sizeof(int2));
    _Float16* Wth[3]; _Float16* Wtl[3];
    for (int i = 0; i < 3; ++i) {
        Wth[i] = (_Float16*)alloc(208 * 224 * sizeof(_Float16));
        Wtl[i] = (_Float16*)alloc(208 * 224 * sizeof(_Float16));
    }

    const int B = 256;
    const int nblk = (N + 255) / 256;   // 196 <= 256
    // CSR build (by destination) + norms; fill consumes rowptr (shifted convention)
    k_zero<<<(N + B - 1) / B, B, 0, stream>>>(cnt, N);
    k_count<<<(E + B - 1) / B, B, 0, stream>>>(ei, cnt, E);
    k_scan1<<<nblk, 256, 0, stream>>>(cnt, rowptr, bsum, N);
    k_scan2<<<1, 256, 0, stream>>>(bsum, nblk);
    k_scan3<<<nblk, 256, 0, stream>>>(rowptr, bsum, cnt, dinv, N);
    k_fill<<<(E + B - 1) / B, B, 0, stream>>>(ei, dinv, rowptr, adj, E);

    // W splits (hi/lo f16, transposed+padded) for layers 1..3, single launch
    dim3 sg((224 * 208 + B - 1) / B, 3);
    k_splitW3<<<sg, B, 0, stream>>>(W1, W2, W3, Wth[0], Wtl[0], Wth[1], Wtl[1], Wth[2], Wtl[2]);

    // layer 0 propagation (4-wide)
    k_gather4<<<(N + B - 1) / B, B, 0, stream>>>(x, dinv, rowptr, adj, px, N);

    // layer 1: GEMM with A synthesized from px@W0+b0, then gather
    k_gemm200_mfma_l0<<<(N + 63) / 64, 256, 0, stream>>>(px, W0, b0, Wth[0], Wtl[0], buf1, N);
    k_gather200<<<(N * 50 + B - 1) / B, B, 0, stream>>>(buf1, dinv, rowptr, adj, buf0, N);

    // layers 2-3
    k_gemm200_mfma<<<(N + 63) / 64, 256, 0, stream>>>(buf0, b1, Wth[1], Wtl[1], buf1, N);
    k_gather200<<<(N * 50 + B - 1) / B, B, 0, stream>>>(buf1, dinv, rowptr, adj, buf0, N);
    k_gemm200_mfma<<<(N + 63) / 64, 256, 0, stream>>>(buf0, b2, Wth[2], Wtl[2], buf1, N);
    k_gather200<<<(N * 50 + B - 1) / B, B, 0, stream>>>(buf1, dinv, rowptr, adj, buf0, N);

    // fused pool (leaky(p3+b3), per-graph mean) + head MLP
    k_poolmlp<<<G, 256, 0, stream>>>(buf0, b3, batch, N, xs, Wl1, bl1, Wl2, bl2, out);
}